// Round 1
// baseline (3677.413 us; speedup 1.0000x reference)
//
#include <hip/hip_runtime.h>
#include <math.h>

// Problem constants
#define HIDN 2048
#define NH   16
#define LATN 512
#define RD   32
#define DHD  128
#define CDIM 96
#define NB   2
#define SEQ  2048
#define MTOT 4096   // NB*SEQ token rows

// ---------------------------------------------------------------------------
// Generic NT GEMM: out[m, col(n)] = sum_k A[m,k] * W[n,k]  (+ optional bias)
// mode 0: col = n           (plain, ldc arbitrary)
// mode 1: col = (n/96)*128 + n%96   (scatter content dims into head layout)
// mode 2: col = n, add bias[n]
// 128x128 tile, BK=16, 256 threads, 8x8 micro-tile per thread, f32.
// ---------------------------------------------------------------------------
#define GBM 128
#define GBN 128
#define GBK 16

__global__ __launch_bounds__(256)
void gemm_nt_f32(const float* __restrict__ A, const float* __restrict__ W,
                 float* __restrict__ out, int M, int N, int K, int ldc,
                 int mode, const float* __restrict__ bias)
{
    __shared__ __align__(16) float As[GBK][GBM + 4];
    __shared__ __align__(16) float Bs[GBK][GBN + 4];
    const int tid = threadIdx.x;
    const int m0 = blockIdx.x * GBM;
    const int n0 = blockIdx.y * GBN;
    const int ty = tid >> 4;      // 0..15 -> rows ty*8..+7
    const int tx = tid & 15;      // 0..15 -> cols tx*8..+7
    const int lrow = tid >> 1;    // 0..127
    const int lk   = (tid & 1) * 8;

    const float* Arow = A + (size_t)(m0 + lrow) * K + lk;
    const float* Wrow = W + (size_t)(n0 + lrow) * K + lk;
    const bool wvalid = (n0 + lrow) < N;

    float acc[8][8];
#pragma unroll
    for (int i = 0; i < 8; ++i)
#pragma unroll
        for (int j = 0; j < 8; ++j) acc[i][j] = 0.f;

    for (int k0 = 0; k0 < K; k0 += GBK) {
        float4 a0 = *(const float4*)(Arow + k0);
        float4 a1 = *(const float4*)(Arow + k0 + 4);
        float4 b0 = make_float4(0.f, 0.f, 0.f, 0.f), b1 = b0;
        if (wvalid) {
            b0 = *(const float4*)(Wrow + k0);
            b1 = *(const float4*)(Wrow + k0 + 4);
        }
        __syncthreads();
        As[lk + 0][lrow] = a0.x; As[lk + 1][lrow] = a0.y;
        As[lk + 2][lrow] = a0.z; As[lk + 3][lrow] = a0.w;
        As[lk + 4][lrow] = a1.x; As[lk + 5][lrow] = a1.y;
        As[lk + 6][lrow] = a1.z; As[lk + 7][lrow] = a1.w;
        Bs[lk + 0][lrow] = b0.x; Bs[lk + 1][lrow] = b0.y;
        Bs[lk + 2][lrow] = b0.z; Bs[lk + 3][lrow] = b0.w;
        Bs[lk + 4][lrow] = b1.x; Bs[lk + 5][lrow] = b1.y;
        Bs[lk + 6][lrow] = b1.z; Bs[lk + 7][lrow] = b1.w;
        __syncthreads();
#pragma unroll
        for (int kk = 0; kk < GBK; ++kk) {
            float4 av0 = *(const float4*)&As[kk][ty * 8];
            float4 av1 = *(const float4*)&As[kk][ty * 8 + 4];
            float4 bv0 = *(const float4*)&Bs[kk][tx * 8];
            float4 bv1 = *(const float4*)&Bs[kk][tx * 8 + 4];
            float av[8] = {av0.x, av0.y, av0.z, av0.w, av1.x, av1.y, av1.z, av1.w};
            float bv[8] = {bv0.x, bv0.y, bv0.z, bv0.w, bv1.x, bv1.y, bv1.z, bv1.w};
#pragma unroll
            for (int i = 0; i < 8; ++i)
#pragma unroll
                for (int j = 0; j < 8; ++j)
                    acc[i][j] += av[i] * bv[j];
        }
    }

#pragma unroll
    for (int i = 0; i < 8; ++i) {
        const int m = m0 + ty * 8 + i;
#pragma unroll
        for (int j = 0; j < 8; ++j) {
            const int n = n0 + tx * 8 + j;
            if (n < N) {
                float v = acc[i][j];
                int col = n;
                if (mode == 1)      col = (n / CDIM) * DHD + (n % CDIM);
                else if (mode == 2) v += bias[n];
                out[(size_t)m * ldc + col] = v;
            }
        }
    }
}

// ---------------------------------------------------------------------------
// RoPE for q: reads qr_tmp[m][h*32+r], writes qq[m][h*128 + 96 + r]
// ---------------------------------------------------------------------------
__global__ void rope_q_kernel(const float* __restrict__ qr, float* __restrict__ qq)
{
    int idx = blockIdx.x * blockDim.x + threadIdx.x; // MTOT*NH*RD threads
    int m = idx >> 9;
    int rem = idx & 511;
    int h = rem >> 5;
    int r = rem & 31;
    int s = m & (SEQ - 1);
    // inv_freq = 10000^(-2*(r%16)/32)
    float invf = expf(-((float)(2 * (r & 15)) / 32.0f) * 9.210340371976184f);
    float f = (float)s * invf;
    float cs = cosf(f), sn = sinf(f);
    float val = qr[(size_t)m * 512 + h * 32 + r];
    float partner = qr[(size_t)m * 512 + h * 32 + (r ^ 16)];
    float rot = (r < 16) ? -partner : partner;
    qq[(size_t)m * HIDN + h * DHD + CDIM + r] = val * cs + rot * sn;
}

// ---------------------------------------------------------------------------
// RoPE for k: reads kr_tmp[m][r], broadcasts to kk[m][h*128 + 96 + r] for all h
// ---------------------------------------------------------------------------
__global__ void rope_k_kernel(const float* __restrict__ kr, float* __restrict__ kk)
{
    int idx = blockIdx.x * blockDim.x + threadIdx.x; // MTOT*RD threads
    int m = idx >> 5;
    int r = idx & 31;
    int s = m & (SEQ - 1);
    float invf = expf(-((float)(2 * (r & 15)) / 32.0f) * 9.210340371976184f);
    float f = (float)s * invf;
    float cs = cosf(f), sn = sinf(f);
    float val = kr[(size_t)m * 32 + r];
    float partner = kr[(size_t)m * 32 + (r ^ 16)];
    float rot = (r < 16) ? -partner : partner;
    float o = val * cs + rot * sn;
    float* dst = kk + (size_t)m * HIDN + CDIM + r;
#pragma unroll
    for (int h = 0; h < NH; ++h) dst[h * DHD] = o;
}

// ---------------------------------------------------------------------------
// Flash-style causal attention. One block = one (b, h, 32-row q-tile).
// BQ=BK=32, D=128. 256 threads: 16x16 grid, each thread 2 S-rows x 2 S-cols,
// O accumulator 2 rows x 8 d-cols in registers. Online softmax in LDS.
// LDS: 3*32*132*4 + 32*36*4 + 3*32*4 = 55.7 KB (fits 64 KB static limit).
// ---------------------------------------------------------------------------
#define BQ  32
#define BKT 32

__global__ __launch_bounds__(256)
void attn_kernel(const float* __restrict__ q, const float* __restrict__ k,
                 const float* __restrict__ v, float* __restrict__ ctx)
{
    const int qt = blockIdx.x;
    const int h  = blockIdx.y;
    const int b  = blockIdx.z;
    const int q0 = qt * BQ;
    __shared__ __align__(16) float Qs[BQ][DHD + 4];
    __shared__ __align__(16) float Ks[BKT][DHD + 4];
    __shared__ __align__(16) float Vs[BKT][DHD + 4];
    __shared__ __align__(16) float Ss[BQ][BKT + 4];
    __shared__ float m_s[BQ], l_s[BQ], al_s[BQ];
    const int tid = threadIdx.x;
    const int ty = tid >> 4, tx = tid & 15;
    const int lrow = tid >> 3, lseg = (tid & 7) * 16;

    {   // load Q tile once
        const float* src = q + (size_t)(b * SEQ + q0 + lrow) * HIDN + h * DHD + lseg;
        *(float4*)&Qs[lrow][lseg]      = *(const float4*)(src);
        *(float4*)&Qs[lrow][lseg + 4]  = *(const float4*)(src + 4);
        *(float4*)&Qs[lrow][lseg + 8]  = *(const float4*)(src + 8);
        *(float4*)&Qs[lrow][lseg + 12] = *(const float4*)(src + 12);
    }
    if (tid < BQ) { m_s[tid] = -3.0e38f; l_s[tid] = 0.f; }
    float o0[8], o1[8];
#pragma unroll
    for (int j = 0; j < 8; ++j) { o0[j] = 0.f; o1[j] = 0.f; }
    __syncthreads();

    for (int kt = 0; kt <= qt; ++kt) {
        const int c0 = kt * BKT;
        {   // load K, V tiles
            const float* ksrc = k + (size_t)(b * SEQ + c0 + lrow) * HIDN + h * DHD + lseg;
            const float* vsrc = v + (size_t)(b * SEQ + c0 + lrow) * HIDN + h * DHD + lseg;
            *(float4*)&Ks[lrow][lseg]      = *(const float4*)(ksrc);
            *(float4*)&Ks[lrow][lseg + 4]  = *(const float4*)(ksrc + 4);
            *(float4*)&Ks[lrow][lseg + 8]  = *(const float4*)(ksrc + 8);
            *(float4*)&Ks[lrow][lseg + 12] = *(const float4*)(ksrc + 12);
            *(float4*)&Vs[lrow][lseg]      = *(const float4*)(vsrc);
            *(float4*)&Vs[lrow][lseg + 4]  = *(const float4*)(vsrc + 4);
            *(float4*)&Vs[lrow][lseg + 8]  = *(const float4*)(vsrc + 8);
            *(float4*)&Vs[lrow][lseg + 12] = *(const float4*)(vsrc + 12);
        }
        __syncthreads();

        // S = Q K^T tile (2x2 per thread)
        float acc00 = 0.f, acc01 = 0.f, acc10 = 0.f, acc11 = 0.f;
        const float* qp0 = &Qs[ty * 2][0];
        const float* qp1 = &Qs[ty * 2 + 1][0];
        const float* kp0 = &Ks[tx * 2][0];
        const float* kp1 = &Ks[tx * 2 + 1][0];
#pragma unroll
        for (int a = 0; a < DHD; a += 4) {
            float4 qa = *(const float4*)(qp0 + a);
            float4 qb = *(const float4*)(qp1 + a);
            float4 ka = *(const float4*)(kp0 + a);
            float4 kb = *(const float4*)(kp1 + a);
            acc00 += qa.x * ka.x + qa.y * ka.y + qa.z * ka.z + qa.w * ka.w;
            acc01 += qa.x * kb.x + qa.y * kb.y + qa.z * kb.z + qa.w * kb.w;
            acc10 += qb.x * ka.x + qb.y * ka.y + qb.z * ka.z + qb.w * ka.w;
            acc11 += qb.x * kb.x + qb.y * kb.y + qb.z * kb.z + qb.w * kb.w;
        }
        const float scale = 0.08838834764831845f; // 1/sqrt(128)
        {
            int r0g = q0 + ty * 2, c0g = c0 + tx * 2;
            float s00 = acc00 * scale; if (c0g     > r0g    ) s00 = -1e30f;
            float s01 = acc01 * scale; if (c0g + 1 > r0g    ) s01 = -1e30f;
            float s10 = acc10 * scale; if (c0g     > r0g + 1) s10 = -1e30f;
            float s11 = acc11 * scale; if (c0g + 1 > r0g + 1) s11 = -1e30f;
            Ss[ty * 2    ][tx * 2    ] = s00;
            Ss[ty * 2    ][tx * 2 + 1] = s01;
            Ss[ty * 2 + 1][tx * 2    ] = s10;
            Ss[ty * 2 + 1][tx * 2 + 1] = s11;
        }
        __syncthreads();

        // online softmax row stats (one thread per row)
        if (tid < BQ) {
            const int r = tid;
            float mold = m_s[r];
            float mt = -3.0e38f;
#pragma unroll 8
            for (int c = 0; c < BKT; ++c) mt = fmaxf(mt, Ss[r][c]);
            float mnew = fmaxf(mold, mt);
            float alpha = __expf(mold - mnew);
            float sum = 0.f;
#pragma unroll 8
            for (int c = 0; c < BKT; ++c) {
                float p = __expf(Ss[r][c] - mnew);
                Ss[r][c] = p;
                sum += p;
            }
            m_s[r] = mnew;
            l_s[r] = alpha * l_s[r] + sum;
            al_s[r] = alpha;
        }
        __syncthreads();

        // O = alpha*O + P V
        {
            float aa = al_s[ty * 2], ab = al_s[ty * 2 + 1];
#pragma unroll
            for (int j = 0; j < 8; ++j) { o0[j] *= aa; o1[j] *= ab; }
#pragma unroll 4
            for (int c = 0; c < BKT; ++c) {
                float p0 = Ss[ty * 2][c], p1 = Ss[ty * 2 + 1][c];
                const float* vp = &Vs[c][tx * 8];
                float4 va = *(const float4*)(vp);
                float4 vb = *(const float4*)(vp + 4);
                o0[0] += p0 * va.x; o0[1] += p0 * va.y; o0[2] += p0 * va.z; o0[3] += p0 * va.w;
                o0[4] += p0 * vb.x; o0[5] += p0 * vb.y; o0[6] += p0 * vb.z; o0[7] += p0 * vb.w;
                o1[0] += p1 * va.x; o1[1] += p1 * va.y; o1[2] += p1 * va.z; o1[3] += p1 * va.w;
                o1[4] += p1 * vb.x; o1[5] += p1 * vb.y; o1[6] += p1 * vb.z; o1[7] += p1 * vb.w;
            }
        }
        __syncthreads(); // protect Ss/Ks/Vs before next iteration's loads
    }

    const float il0 = 1.0f / l_s[ty * 2];
    const float il1 = 1.0f / l_s[ty * 2 + 1];
    float* d0 = ctx + (size_t)(b * SEQ + q0 + ty * 2) * HIDN + h * DHD + tx * 8;
    float* d1 = d0 + HIDN;
#pragma unroll
    for (int j = 0; j < 8; ++j) { d0[j] = o0[j] * il0; d1[j] = o1[j] * il1; }
}

// ---------------------------------------------------------------------------
extern "C" void kernel_launch(void* const* d_in, const int* in_sizes, int n_in,
                              void* d_out, int out_size, void* d_ws, size_t ws_size,
                              hipStream_t stream)
{
    const float* x        = (const float*)d_in[0];
    const float* Wq_down  = (const float*)d_in[1];
    const float* Wq_up    = (const float*)d_in[2];
    const float* Wq_rope  = (const float*)d_in[3];
    const float* Wkv_down = (const float*)d_in[4];
    const float* Wk_up    = (const float*)d_in[5];
    const float* Wk_rope  = (const float*)d_in[6];
    const float* Wv_up    = (const float*)d_in[7];
    const float* Wo       = (const float*)d_in[8];
    const float* bo       = (const float*)d_in[9];
    float* out = (float*)d_out;

    // workspace layout (floats); qr_tmp/kr_tmp alias ctx (dead before attention)
    float* ws     = (float*)d_ws;
    float* q_lat  = ws;               // 4096*512
    float* kv_lat = ws + 2097152;     // 4096*512
    float* qq     = ws + 4194304;     // 4096*2048
    float* kk     = ws + 12582912;    // 4096*2048
    float* vv     = ws + 20971520;    // 4096*2048
    float* ctx    = ws + 29360128;    // 4096*2048
    float* qr_tmp = ctx;              // 4096*512, used pre-attention only
    float* kr_tmp = ctx + 2097152;    // 4096*32,  used pre-attention only

    dim3 blk(256);
    // latent projections
    gemm_nt_f32<<<dim3(32,  4), blk, 0, stream>>>(x, Wq_down, q_lat, MTOT, LATN, HIDN, LATN, 0, nullptr);
    gemm_nt_f32<<<dim3(32,  4), blk, 0, stream>>>(x, Wkv_down, kv_lat, MTOT, LATN, HIDN, LATN, 0, nullptr);
    // q content (scatter into 128-dim head layout) + q rope raw
    gemm_nt_f32<<<dim3(32, 12), blk, 0, stream>>>(q_lat, Wq_up, qq, MTOT, 1536, LATN, HIDN, 1, nullptr);
    gemm_nt_f32<<<dim3(32,  4), blk, 0, stream>>>(q_lat, Wq_rope, qr_tmp, MTOT, 512, LATN, 512, 0, nullptr);
    // k content + k rope raw (from x) + v
    gemm_nt_f32<<<dim3(32, 12), blk, 0, stream>>>(kv_lat, Wk_up, kk, MTOT, 1536, LATN, HIDN, 1, nullptr);
    gemm_nt_f32<<<dim3(32,  1), blk, 0, stream>>>(x, Wk_rope, kr_tmp, MTOT, 32, HIDN, 32, 0, nullptr);
    gemm_nt_f32<<<dim3(32, 16), blk, 0, stream>>>(kv_lat, Wv_up, vv, MTOT, HIDN, LATN, HIDN, 0, nullptr);
    // rope
    rope_q_kernel<<<dim3(MTOT * NH * RD / 256), blk, 0, stream>>>(qr_tmp, qq);
    rope_k_kernel<<<dim3(MTOT * RD / 256), blk, 0, stream>>>(kr_tmp, kk);
    // attention
    attn_kernel<<<dim3(SEQ / BQ, NH, NB), blk, 0, stream>>>(qq, kk, vv, ctx);
    // output projection + bias
    gemm_nt_f32<<<dim3(32, 16), blk, 0, stream>>>(ctx, Wo, out, MTOT, HIDN, HIDN, HIDN, 2, bo);
}

// Round 2
// 2201.133 us; speedup vs baseline: 1.6707x; 1.6707x over previous
//
#include <hip/hip_runtime.h>
#include <math.h>

// Problem constants
#define HIDN 2048
#define NH   16
#define LATN 512
#define RD   32
#define DHD  128
#define CDIM 96
#define NB   2
#define SEQ  2048
#define MTOT 4096   // NB*SEQ token rows

typedef __attribute__((ext_vector_type(8))) short bf8_t;   // 8 x bf16 (4 VGPRs)
typedef __attribute__((ext_vector_type(4))) float f4_t;    // MFMA C/D frag

__device__ __forceinline__ short f2bf(float f) {
    union { float f; unsigned u; } x; x.f = f;
    unsigned r = x.u + 0x7fffu + ((x.u >> 16) & 1u);   // round-to-nearest-even
    return (short)(r >> 16);
}

// ---------------------------------------------------------------------------
// Generic NT GEMM (f32): out[m, col(n)] = sum_k A[m,k] * W[n,k]  (+ bias)
// mode 0: col = n; mode 1: col = (n/96)*128 + n%96; mode 2: col = n, +bias
// ---------------------------------------------------------------------------
#define GBM 128
#define GBN 128
#define GBK 16

__global__ __launch_bounds__(256)
void gemm_nt_f32(const float* __restrict__ A, const float* __restrict__ W,
                 float* __restrict__ out, int M, int N, int K, int ldc,
                 int mode, const float* __restrict__ bias)
{
    __shared__ __align__(16) float As[GBK][GBM + 4];
    __shared__ __align__(16) float Bs[GBK][GBN + 4];
    const int tid = threadIdx.x;
    const int m0 = blockIdx.x * GBM;
    const int n0 = blockIdx.y * GBN;
    const int ty = tid >> 4;
    const int tx = tid & 15;
    const int lrow = tid >> 1;
    const int lk   = (tid & 1) * 8;

    const float* Arow = A + (size_t)(m0 + lrow) * K + lk;
    const float* Wrow = W + (size_t)(n0 + lrow) * K + lk;
    const bool wvalid = (n0 + lrow) < N;

    float acc[8][8];
#pragma unroll
    for (int i = 0; i < 8; ++i)
#pragma unroll
        for (int j = 0; j < 8; ++j) acc[i][j] = 0.f;

    for (int k0 = 0; k0 < K; k0 += GBK) {
        float4 a0 = *(const float4*)(Arow + k0);
        float4 a1 = *(const float4*)(Arow + k0 + 4);
        float4 b0 = make_float4(0.f, 0.f, 0.f, 0.f), b1 = b0;
        if (wvalid) {
            b0 = *(const float4*)(Wrow + k0);
            b1 = *(const float4*)(Wrow + k0 + 4);
        }
        __syncthreads();
        As[lk + 0][lrow] = a0.x; As[lk + 1][lrow] = a0.y;
        As[lk + 2][lrow] = a0.z; As[lk + 3][lrow] = a0.w;
        As[lk + 4][lrow] = a1.x; As[lk + 5][lrow] = a1.y;
        As[lk + 6][lrow] = a1.z; As[lk + 7][lrow] = a1.w;
        Bs[lk + 0][lrow] = b0.x; Bs[lk + 1][lrow] = b0.y;
        Bs[lk + 2][lrow] = b0.z; Bs[lk + 3][lrow] = b0.w;
        Bs[lk + 4][lrow] = b1.x; Bs[lk + 5][lrow] = b1.y;
        Bs[lk + 6][lrow] = b1.z; Bs[lk + 7][lrow] = b1.w;
        __syncthreads();
#pragma unroll
        for (int kk = 0; kk < GBK; ++kk) {
            float4 av0 = *(const float4*)&As[kk][ty * 8];
            float4 av1 = *(const float4*)&As[kk][ty * 8 + 4];
            float4 bv0 = *(const float4*)&Bs[kk][tx * 8];
            float4 bv1 = *(const float4*)&Bs[kk][tx * 8 + 4];
            float av[8] = {av0.x, av0.y, av0.z, av0.w, av1.x, av1.y, av1.z, av1.w};
            float bv[8] = {bv0.x, bv0.y, bv0.z, bv0.w, bv1.x, bv1.y, bv1.z, bv1.w};
#pragma unroll
            for (int i = 0; i < 8; ++i)
#pragma unroll
                for (int j = 0; j < 8; ++j)
                    acc[i][j] += av[i] * bv[j];
        }
    }

#pragma unroll
    for (int i = 0; i < 8; ++i) {
        const int m = m0 + ty * 8 + i;
#pragma unroll
        for (int j = 0; j < 8; ++j) {
            const int n = n0 + tx * 8 + j;
            if (n < N) {
                float v = acc[i][j];
                int col = n;
                if (mode == 1)      col = (n / CDIM) * DHD + (n % CDIM);
                else if (mode == 2) v += bias[n];
                out[(size_t)m * ldc + col] = v;
            }
        }
    }
}

// ---------------------------------------------------------------------------
// RoPE for q: reads qr_tmp[m][h*32+r], writes qq[m][h*128 + 96 + r]
// ---------------------------------------------------------------------------
__global__ void rope_q_kernel(const float* __restrict__ qr, float* __restrict__ qq)
{
    int idx = blockIdx.x * blockDim.x + threadIdx.x;
    int m = idx >> 9;
    int rem = idx & 511;
    int h = rem >> 5;
    int r = rem & 31;
    int s = m & (SEQ - 1);
    float invf = expf(-((float)(2 * (r & 15)) / 32.0f) * 9.210340371976184f);
    float f = (float)s * invf;
    float cs = cosf(f), sn = sinf(f);
    float val = qr[(size_t)m * 512 + h * 32 + r];
    float partner = qr[(size_t)m * 512 + h * 32 + (r ^ 16)];
    float rot = (r < 16) ? -partner : partner;
    qq[(size_t)m * HIDN + h * DHD + CDIM + r] = val * cs + rot * sn;
}

__global__ void rope_k_kernel(const float* __restrict__ kr, float* __restrict__ kk)
{
    int idx = blockIdx.x * blockDim.x + threadIdx.x;
    int m = idx >> 5;
    int r = idx & 31;
    int s = m & (SEQ - 1);
    float invf = expf(-((float)(2 * (r & 15)) / 32.0f) * 9.210340371976184f);
    float f = (float)s * invf;
    float cs = cosf(f), sn = sinf(f);
    float val = kr[(size_t)m * 32 + r];
    float partner = kr[(size_t)m * 32 + (r ^ 16)];
    float rot = (r < 16) ? -partner : partner;
    float o = val * cs + rot * sn;
    float* dst = kk + (size_t)m * HIDN + CDIM + r;
#pragma unroll
    for (int h = 0; h < NH; ++h) dst[h * DHD] = o;
}

// ---------------------------------------------------------------------------
// MFMA flash attention (bf16 compute, f32 accumulate).
// Block = 256 threads = 4 waves. BQ=64 (16 q-rows per wave), BK=32, D=128.
// Q A-frags in registers (pre-scaled by 1/sqrt(D)). K in LDS [32][128+8]
// (pad kills the 256B-stride bank collision). V transposed in LDS [128][32+8]
// so PV B-frags are contiguous ds_read_b128. P does the C-layout -> A-layout
// transform through a per-wave LDS buffer (no barrier needed: same wave).
// Online softmax per-lane in registers: C-layout row = quad*4+reg, col=lane&15;
// row reductions are 4 shfl_xor over the 16-lane group.
// LDS total ~24 KB.
// ---------------------------------------------------------------------------
#define ABQ 64
#define ABK 32
#define KPITCH 136   // shorts per Ks row (128 + 8)
#define VPITCH 40    // shorts per Vt/Ps row (32 + 8)

__global__ __launch_bounds__(256)
void attn_mfma(const float* __restrict__ q, const float* __restrict__ k,
               const float* __restrict__ v, float* __restrict__ ctx)
{
    const int qb = blockIdx.x, h = blockIdx.y, b = blockIdx.z;
    const int q0 = qb * ABQ;
    __shared__ __align__(16) short Ks[ABK][KPITCH];
    __shared__ __align__(16) short Vt[DHD][VPITCH];
    __shared__ __align__(16) short Ps[4][16][VPITCH];
    const int tid  = threadIdx.x;
    const int w    = tid >> 6;
    const int lane = tid & 63;
    const int l16  = lane & 15;
    const int quad = lane >> 4;
    const float scale = 0.08838834764831845f;  // 1/sqrt(128)

    // Q A-fragments: A[m=lane&15][k=quad*8+j], 4 k-steps cover D=128
    bf8_t qf[4];
    {
        const float* qp = q + (size_t)(b * SEQ + q0 + w * 16 + l16) * HIDN
                            + h * DHD + quad * 8;
#pragma unroll
        for (int ks = 0; ks < 4; ++ks)
#pragma unroll
            for (int j = 0; j < 8; ++j)
                qf[ks][j] = f2bf(qp[ks * 32 + j] * scale);
    }

    f4_t O[8];
#pragma unroll
    for (int i = 0; i < 8; ++i) O[i] = (f4_t){0.f, 0.f, 0.f, 0.f};
    float m_run[4], l_run[4];
#pragma unroll
    for (int r = 0; r < 4; ++r) { m_run[r] = -3e38f; l_run[r] = 0.f; }

    const int ntiles = (q0 + ABQ) / ABK;
    const int srow = tid >> 3;          // staging: k-token row 0..31
    const int dseg = (tid & 7) * 16;    // staging: d-offset 0..112

    for (int kt = 0; kt < ntiles; ++kt) {
        const int c0 = kt * ABK;
        {   // stage K (row-major) and V (transposed), f32 -> bf16
            const float* kp = k + (size_t)(b * SEQ + c0 + srow) * HIDN + h * DHD + dseg;
            const float* vp = v + (size_t)(b * SEQ + c0 + srow) * HIDN + h * DHD + dseg;
            short tk[16];
#pragma unroll
            for (int j = 0; j < 16; ++j) tk[j] = f2bf(kp[j]);
            *(int4*)&Ks[srow][dseg]     = *(int4*)&tk[0];
            *(int4*)&Ks[srow][dseg + 8] = *(int4*)&tk[8];
#pragma unroll
            for (int j = 0; j < 16; ++j) Vt[dseg + j][srow] = f2bf(vp[j]);
        }
        __syncthreads();

        // S = Q K^T : this wave's 16 rows x 32 cols (2 n-tiles x 4 k-steps)
        f4_t S0 = {0.f, 0.f, 0.f, 0.f}, S1 = {0.f, 0.f, 0.f, 0.f};
#pragma unroll
        for (int ks = 0; ks < 4; ++ks) {
            bf8_t b0 = *(const bf8_t*)&Ks[l16][ks * 32 + quad * 8];
            bf8_t b1 = *(const bf8_t*)&Ks[l16 + 16][ks * 32 + quad * 8];
            S0 = __builtin_amdgcn_mfma_f32_16x16x32_bf16(qf[ks], b0, S0, 0, 0, 0);
            S1 = __builtin_amdgcn_mfma_f32_16x16x32_bf16(qf[ks], b1, S1, 0, 0, 0);
        }

        // causal mask + online softmax (C layout: row=quad*4+r, col=l16 / l16+16)
        const int grow0 = q0 + w * 16 + quad * 4;
        float alpha[4];
#pragma unroll
        for (int r = 0; r < 4; ++r) {
            const int grow = grow0 + r;
            float s0 = (c0 + l16      <= grow) ? S0[r] : -3e38f;
            float s1 = (c0 + l16 + 16 <= grow) ? S1[r] : -3e38f;
            float mx = fmaxf(s0, s1);
            mx = fmaxf(mx, __shfl_xor(mx, 1));
            mx = fmaxf(mx, __shfl_xor(mx, 2));
            mx = fmaxf(mx, __shfl_xor(mx, 4));
            mx = fmaxf(mx, __shfl_xor(mx, 8));
            const float mnew = fmaxf(m_run[r], mx);
            alpha[r] = __expf(m_run[r] - mnew);
            const float p0 = __expf(s0 - mnew);
            const float p1 = __expf(s1 - mnew);
            float rs = p0 + p1;
            rs += __shfl_xor(rs, 1);
            rs += __shfl_xor(rs, 2);
            rs += __shfl_xor(rs, 4);
            rs += __shfl_xor(rs, 8);
            l_run[r] = alpha[r] * l_run[r] + rs;
            m_run[r] = mnew;
            Ps[w][quad * 4 + r][l16]      = f2bf(p0);
            Ps[w][quad * 4 + r][l16 + 16] = f2bf(p1);
        }

        // rescale O by alpha (O C-layout rows match reg index r)
#pragma unroll
        for (int dt = 0; dt < 8; ++dt)
#pragma unroll
            for (int r = 0; r < 4; ++r) O[dt][r] *= alpha[r];

        // PV: A-frag = P row (whole BK=32 in one mfma), B-frag from Vt
        bf8_t pf = *(const bf8_t*)&Ps[w][l16][quad * 8];
#pragma unroll
        for (int dt = 0; dt < 8; ++dt) {
            bf8_t vf = *(const bf8_t*)&Vt[dt * 16 + l16][quad * 8];
            O[dt] = __builtin_amdgcn_mfma_f32_16x16x32_bf16(pf, vf, O[dt], 0, 0, 0);
        }
        __syncthreads();  // protect Ks/Vt before next tile's staging
    }

    // epilogue: O / l
    float inv_l[4];
#pragma unroll
    for (int r = 0; r < 4; ++r) inv_l[r] = 1.0f / l_run[r];
    float* cbase = ctx + (size_t)(b * SEQ + q0 + w * 16 + quad * 4) * HIDN
                       + h * DHD + l16;
#pragma unroll
    for (int r = 0; r < 4; ++r)
#pragma unroll
        for (int dt = 0; dt < 8; ++dt)
            cbase[(size_t)r * HIDN + dt * 16] = O[dt][r] * inv_l[r];
}

// ---------------------------------------------------------------------------
extern "C" void kernel_launch(void* const* d_in, const int* in_sizes, int n_in,
                              void* d_out, int out_size, void* d_ws, size_t ws_size,
                              hipStream_t stream)
{
    const float* x        = (const float*)d_in[0];
    const float* Wq_down  = (const float*)d_in[1];
    const float* Wq_up    = (const float*)d_in[2];
    const float* Wq_rope  = (const float*)d_in[3];
    const float* Wkv_down = (const float*)d_in[4];
    const float* Wk_up    = (const float*)d_in[5];
    const float* Wk_rope  = (const float*)d_in[6];
    const float* Wv_up    = (const float*)d_in[7];
    const float* Wo       = (const float*)d_in[8];
    const float* bo       = (const float*)d_in[9];
    float* out = (float*)d_out;

    float* ws     = (float*)d_ws;
    float* q_lat  = ws;               // 4096*512
    float* kv_lat = ws + 2097152;     // 4096*512
    float* qq     = ws + 4194304;     // 4096*2048
    float* kk     = ws + 12582912;    // 4096*2048
    float* vv     = ws + 20971520;    // 4096*2048
    float* ctx    = ws + 29360128;    // 4096*2048
    float* qr_tmp = ctx;              // 4096*512, pre-attention only
    float* kr_tmp = ctx + 2097152;    // 4096*32,  pre-attention only

    dim3 blk(256);
    gemm_nt_f32<<<dim3(32,  4), blk, 0, stream>>>(x, Wq_down, q_lat, MTOT, LATN, HIDN, LATN, 0, nullptr);
    gemm_nt_f32<<<dim3(32,  4), blk, 0, stream>>>(x, Wkv_down, kv_lat, MTOT, LATN, HIDN, LATN, 0, nullptr);
    gemm_nt_f32<<<dim3(32, 12), blk, 0, stream>>>(q_lat, Wq_up, qq, MTOT, 1536, LATN, HIDN, 1, nullptr);
    gemm_nt_f32<<<dim3(32,  4), blk, 0, stream>>>(q_lat, Wq_rope, qr_tmp, MTOT, 512, LATN, 512, 0, nullptr);
    gemm_nt_f32<<<dim3(32, 12), blk, 0, stream>>>(kv_lat, Wk_up, kk, MTOT, 1536, LATN, HIDN, 1, nullptr);
    gemm_nt_f32<<<dim3(32,  1), blk, 0, stream>>>(x, Wk_rope, kr_tmp, MTOT, 32, HIDN, 32, 0, nullptr);
    gemm_nt_f32<<<dim3(32, 16), blk, 0, stream>>>(kv_lat, Wv_up, vv, MTOT, HIDN, LATN, HIDN, 0, nullptr);
    rope_q_kernel<<<dim3(MTOT * NH * RD / 256), blk, 0, stream>>>(qr_tmp, qq);
    rope_k_kernel<<<dim3(MTOT * RD / 256), blk, 0, stream>>>(kr_tmp, kk);
    attn_mfma<<<dim3(SEQ / ABQ, NH, NB), blk, 0, stream>>>(qq, kk, vv, ctx);
    gemm_nt_f32<<<dim3(32, 16), blk, 0, stream>>>(ctx, Wo, out, MTOT, HIDN, HIDN, HIDN, 2, bo);
}

// Round 3
// 627.544 us; speedup vs baseline: 5.8600x; 3.5075x over previous
//
#include <hip/hip_runtime.h>
#include <math.h>

// Problem constants
#define HIDN 2048
#define NH   16
#define LATN 512
#define RD   32
#define DHD  128
#define CDIM 96
#define NB   2
#define SEQ  2048
#define MTOT 4096   // NB*SEQ token rows

typedef __attribute__((ext_vector_type(8))) short bf8_t;   // 8 x bf16 (4 VGPRs)
typedef __attribute__((ext_vector_type(4))) float f4_t;    // MFMA C/D frag
typedef __attribute__((ext_vector_type(4))) short s4_t;    // 4 x bf16 (8 B)

__device__ __forceinline__ short f2bf(float f) {
    union { float f; unsigned u; } x; x.f = f;
    unsigned r = x.u + 0x7fffu + ((x.u >> 16) & 1u);   // round-to-nearest-even
    return (short)(r >> 16);
}
__device__ __forceinline__ float bf2f(short s) {
    union { float f; unsigned u; } x; x.u = ((unsigned)(unsigned short)s) << 16;
    return x.f;
}
// async global->LDS, 16B per lane, lane i lands at ldsbase + i*16
__device__ __forceinline__ void gload16(const void* g, void* l) {
    __builtin_amdgcn_global_load_lds(
        (const __attribute__((address_space(1))) void*)g,
        (__attribute__((address_space(3))) void*)l, 16, 0, 0);
}

// ---------------------------------------------------------------------------
// f32 -> bf16 conversion for x + all 8 weights, one launch.
// Each block converts 2048 elements (256 thr x 8). Ranges precomputed.
// ---------------------------------------------------------------------------
__global__ __launch_bounds__(256)
void cvt_all(const float* __restrict__ x,  const float* __restrict__ w0,
             const float* __restrict__ w1, const float* __restrict__ w2,
             const float* __restrict__ w3, const float* __restrict__ w4,
             const float* __restrict__ w5, const float* __restrict__ w6,
             const float* __restrict__ w7,
             short* xb, short* o0, short* o1, short* o2, short* o3,
             short* o4, short* o5, short* o6, short* o7)
{
    int bid = blockIdx.x;
    const float* src; short* dst; int rel;
    if      (bid < 4096) { src = x;  dst = xb; rel = bid; }
    else if (bid < 4608) { src = w0; dst = o0; rel = bid - 4096; }
    else if (bid < 4992) { src = w1; dst = o1; rel = bid - 4608; }
    else if (bid < 5120) { src = w2; dst = o2; rel = bid - 4992; }
    else if (bid < 5632) { src = w3; dst = o3; rel = bid - 5120; }
    else if (bid < 6016) { src = w4; dst = o4; rel = bid - 5632; }
    else if (bid < 6048) { src = w5; dst = o5; rel = bid - 6016; }
    else if (bid < 6560) { src = w6; dst = o6; rel = bid - 6048; }
    else                 { src = w7; dst = o7; rel = bid - 6560; }
    int base = rel * 2048 + threadIdx.x * 8;
    float4 a = *(const float4*)(src + base);
    float4 b = *(const float4*)(src + base + 4);
    s4_t r0 = { f2bf(a.x), f2bf(a.y), f2bf(a.z), f2bf(a.w) };
    s4_t r1 = { f2bf(b.x), f2bf(b.y), f2bf(b.z), f2bf(b.w) };
    *(s4_t*)(dst + base)     = r0;
    *(s4_t*)(dst + base + 4) = r1;
}

// ---------------------------------------------------------------------------
// bf16 MFMA NT GEMM (m97 recipe): out[m,col(n)] = sum_k A[m,k]*W[n,k]
// 128x128 tile, BK=32, 256 thr = 4 waves, 4x4 16x16x32 frags per wave.
// global_load_lds staging with XOR-swizzled chunk layout:
//   LDS chunk c (16B units) holds (row = c>>2, kc = (c&3) ^ (row&3)).
//   Frag read (row, kc=quad) -> conflict-free ds_read_b128.
// modes: 0 bf16 plain | 1 bf16 head-scatter (n -> (n/96)*128+n%96)
//        2 f32 + bias | 3 bf16 transposed V store vT[b][n][s] | 4 bf16 N-guard
// ---------------------------------------------------------------------------
__global__ __launch_bounds__(256)
void gemm_bf16(const short* __restrict__ A, const short* __restrict__ W,
               void* __restrict__ outp, int M, int N, int K, int ldc,
               int mode, const float* __restrict__ bias)
{
    __shared__ short As[128 * 32];
    __shared__ short Bs[128 * 32];
    const int tid  = threadIdx.x;
    const int w    = tid >> 6;
    const int lane = tid & 63;
    const int l16  = lane & 15;
    const int quad = lane >> 4;
    const int m0 = blockIdx.x * 128;
    const int n0 = blockIdx.y * 128;
    const int wm = (w & 1) * 64;
    const int wn = (w >> 1) * 64;

    // staging: wave w stages rows w*32 .. w*32+31 of A and B (2 instrs each)
    int srow[2], skc[2];
#pragma unroll
    for (int j = 0; j < 2; ++j) {
        int c = (w * 32 + j * 16) * 4 + lane;   // global chunk index
        srow[j] = c >> 2;
        skc[j]  = (c & 3) ^ (srow[j] & 3);
    }
    const int xq = quad ^ (l16 & 3);   // swizzled kc for frag reads

    f4_t acc[4][4];
#pragma unroll
    for (int i = 0; i < 4; ++i)
#pragma unroll
        for (int j = 0; j < 4; ++j) acc[i][j] = (f4_t){0.f, 0.f, 0.f, 0.f};

    for (int k0 = 0; k0 < K; k0 += 32) {
        __syncthreads();
#pragma unroll
        for (int j = 0; j < 2; ++j) {
            const short* ga = A + (size_t)(m0 + srow[j]) * K + k0 + skc[j] * 8;
            gload16(ga, &As[(w * 32 + j * 16) * 4 * 8]);
            int gn = n0 + srow[j]; if (gn >= N) gn = N - 1;
            const short* gb = W + (size_t)gn * K + k0 + skc[j] * 8;
            gload16(gb, &Bs[(w * 32 + j * 16) * 4 * 8]);
        }
        __syncthreads();
        bf8_t af[4], bfr[4];
#pragma unroll
        for (int i = 0; i < 4; ++i)
            af[i] = *(const bf8_t*)&As[((wm + i * 16 + l16) * 4 + xq) * 8];
#pragma unroll
        for (int j = 0; j < 4; ++j)
            bfr[j] = *(const bf8_t*)&Bs[((wn + j * 16 + l16) * 4 + xq) * 8];
#pragma unroll
        for (int i = 0; i < 4; ++i)
#pragma unroll
            for (int j = 0; j < 4; ++j)
                acc[i][j] = __builtin_amdgcn_mfma_f32_16x16x32_bf16(
                    af[i], bfr[j], acc[i][j], 0, 0, 0);
    }

    // epilogue (C layout: col = l16, row = quad*4 + r)
#pragma unroll
    for (int mi = 0; mi < 4; ++mi) {
#pragma unroll
        for (int nj = 0; nj < 4; ++nj) {
            const int gm = m0 + wm + mi * 16 + quad * 4;
            const int gn = n0 + wn + nj * 16 + l16;
            if (mode == 0) {
                short* o = (short*)outp + (size_t)gm * ldc + gn;
#pragma unroll
                for (int r = 0; r < 4; ++r) o[(size_t)r * ldc] = f2bf(acc[mi][nj][r]);
            } else if (mode == 1) {
                int col = (gn / CDIM) * DHD + (gn % CDIM);
                short* o = (short*)outp + (size_t)gm * ldc + col;
#pragma unroll
                for (int r = 0; r < 4; ++r) o[(size_t)r * ldc] = f2bf(acc[mi][nj][r]);
            } else if (mode == 2) {
                float* o = (float*)outp + (size_t)gm * ldc + gn;
                float bb = bias[gn];
#pragma unroll
                for (int r = 0; r < 4; ++r) o[(size_t)r * ldc] = acc[mi][nj][r] + bb;
            } else if (mode == 3) {
                // vT[b][n][s]: b = gm>>11, s = gm&2047 (4 consecutive s)
                size_t idx = ((size_t)((gm >> 11) * 2048 + gn)) * 2048 + (gm & 2047);
                s4_t pk = { f2bf(acc[mi][nj][0]), f2bf(acc[mi][nj][1]),
                            f2bf(acc[mi][nj][2]), f2bf(acc[mi][nj][3]) };
                *(s4_t*)((short*)outp + idx) = pk;
            } else { // mode 4
                if (gn < N) {
                    short* o = (short*)outp + (size_t)gm * ldc + gn;
#pragma unroll
                    for (int r = 0; r < 4; ++r) o[(size_t)r * ldc] = f2bf(acc[mi][nj][r]);
                }
            }
        }
    }
}

// ---------------------------------------------------------------------------
// RoPE (bf16 in/out)
// ---------------------------------------------------------------------------
__global__ void rope_q_kernel(const short* __restrict__ qr, short* __restrict__ qq)
{
    int idx = blockIdx.x * blockDim.x + threadIdx.x;
    int m = idx >> 9;
    int rem = idx & 511;
    int h = rem >> 5;
    int r = rem & 31;
    int s = m & (SEQ - 1);
    float invf = expf(-((float)(2 * (r & 15)) / 32.0f) * 9.210340371976184f);
    float f = (float)s * invf;
    float cs = cosf(f), sn = sinf(f);
    float val = bf2f(qr[(size_t)m * 512 + h * 32 + r]);
    float partner = bf2f(qr[(size_t)m * 512 + h * 32 + (r ^ 16)]);
    float rot = (r < 16) ? -partner : partner;
    qq[(size_t)m * HIDN + h * DHD + CDIM + r] = f2bf(val * cs + rot * sn);
}

__global__ void rope_k_kernel(const short* __restrict__ kr, short* __restrict__ kk)
{
    int idx = blockIdx.x * blockDim.x + threadIdx.x;
    int m = idx >> 5;
    int r = idx & 31;
    int s = m & (SEQ - 1);
    float invf = expf(-((float)(2 * (r & 15)) / 32.0f) * 9.210340371976184f);
    float f = (float)s * invf;
    float cs = cosf(f), sn = sinf(f);
    float val = bf2f(kr[(size_t)m * 32 + r]);
    float partner = bf2f(kr[(size_t)m * 32 + (r ^ 16)]);
    float rot = (r < 16) ? -partner : partner;
    short o = f2bf(val * cs + rot * sn);
    short* dst = kk + (size_t)m * HIDN + CDIM + r;
#pragma unroll
    for (int h = 0; h < NH; ++h) dst[h * DHD] = o;
}

// ---------------------------------------------------------------------------
// MFMA flash attention, bf16 inputs. 4 waves, BQ=64 (16 rows/wave), BK=32.
// K tile: swizzled global_load_lds, LDS chunk c = (key = c>>4,
//   dchunk = (c&8)|((c&7)^(key&7))) -> conflict-free B-frag reads.
// V tile from pre-transposed vT[b][h][d][s]: chunk c = (d = c>>2,
//   kc = (c&3)^(d&3)).
// Scale applied to f32 scores (Q stays raw bf16).
// ---------------------------------------------------------------------------
__global__ __launch_bounds__(256)
void attn_mfma(const short* __restrict__ q, const short* __restrict__ k,
               const short* __restrict__ vt, short* __restrict__ ctx)
{
    const int qb = blockIdx.x, h = blockIdx.y, b = blockIdx.z;
    const int q0 = qb * 64;
    __shared__ short Ks[32 * 128];
    __shared__ short Vs[128 * 32];
    __shared__ short Ps[4][16][40];
    const int tid  = threadIdx.x;
    const int w    = tid >> 6;
    const int lane = tid & 63;
    const int l16  = lane & 15;
    const int quad = lane >> 4;
    const float scale = 0.08838834764831845f;  // 1/sqrt(128)

    // Q A-frags straight from global bf16 (A[m=l16][k=quad*8+j], 4 k-steps)
    bf8_t qf[4];
    {
        const short* qp = q + (size_t)(b * SEQ + q0 + w * 16 + l16) * HIDN
                            + h * DHD + quad * 8;
#pragma unroll
        for (int ks = 0; ks < 4; ++ks) qf[ks] = *(const bf8_t*)(qp + ks * 32);
    }

    f4_t O[8];
#pragma unroll
    for (int i = 0; i < 8; ++i) O[i] = (f4_t){0.f, 0.f, 0.f, 0.f};
    float m_run[4], l_run[4];
#pragma unroll
    for (int r = 0; r < 4; ++r) { m_run[r] = -3e38f; l_run[r] = 0.f; }

    // staging lane decode (2 chunks per lane for K, 2 for V)
    int kkey[2], kdch[2], vdd[2], vkc[2];
#pragma unroll
    for (int j = 0; j < 2; ++j) {
        int c = w * 128 + j * 64 + lane;
        int key = c >> 4, dcp = c & 15;
        kkey[j] = key;
        kdch[j] = (dcp & 8) | ((dcp & 7) ^ (key & 7));
        int d = c >> 2;
        vdd[j] = d;
        vkc[j] = (c & 3) ^ (d & 3);
    }
    const size_t kbase = (size_t)(b * SEQ) * HIDN + h * DHD;
    const size_t vbase = (size_t)(b * NH + h) * DHD * SEQ;
    const int xq = quad;  // frag k-chunk within 32-k step

    const int ntiles = (q0 + 64) / 32;
    for (int kt = 0; kt < ntiles; ++kt) {
        const int c0 = kt * 32;
        __syncthreads();
#pragma unroll
        for (int j = 0; j < 2; ++j) {
            const short* gk = k + kbase + (size_t)(c0 + kkey[j]) * HIDN + kdch[j] * 8;
            gload16(gk, &Ks[(w * 128 + j * 64) * 8]);
            const short* gv = vt + vbase + (size_t)vdd[j] * SEQ + c0 + vkc[j] * 8;
            gload16(gv, &Vs[(w * 128 + j * 64) * 8]);
        }
        __syncthreads();

        // S = Q K^T : 16 rows x 32 cols (2 n-tiles x 4 k-steps)
        f4_t S0 = {0.f, 0.f, 0.f, 0.f}, S1 = {0.f, 0.f, 0.f, 0.f};
#pragma unroll
        for (int ks = 0; ks < 4; ++ks) {
            int dch = ks * 4 + xq;
            int sw  = (dch & 8) | ((dch & 7) ^ (l16 & 7));
            bf8_t b0 = *(const bf8_t*)&Ks[(l16 * 16 + sw) * 8];
            bf8_t b1 = *(const bf8_t*)&Ks[((l16 + 16) * 16 + sw) * 8];
            S0 = __builtin_amdgcn_mfma_f32_16x16x32_bf16(qf[ks], b0, S0, 0, 0, 0);
            S1 = __builtin_amdgcn_mfma_f32_16x16x32_bf16(qf[ks], b1, S1, 0, 0, 0);
        }

        // causal mask + online softmax (C layout: row=quad*4+r, col=l16/l16+16)
        const int grow0 = q0 + w * 16 + quad * 4;
        float alpha[4];
#pragma unroll
        for (int r = 0; r < 4; ++r) {
            const int grow = grow0 + r;
            float s0 = (c0 + l16      <= grow) ? S0[r] * scale : -3e38f;
            float s1 = (c0 + l16 + 16 <= grow) ? S1[r] * scale : -3e38f;
            float mx = fmaxf(s0, s1);
            mx = fmaxf(mx, __shfl_xor(mx, 1));
            mx = fmaxf(mx, __shfl_xor(mx, 2));
            mx = fmaxf(mx, __shfl_xor(mx, 4));
            mx = fmaxf(mx, __shfl_xor(mx, 8));
            const float mnew = fmaxf(m_run[r], mx);
            alpha[r] = __expf(m_run[r] - mnew);
            const float p0 = __expf(s0 - mnew);
            const float p1 = __expf(s1 - mnew);
            float rs = p0 + p1;
            rs += __shfl_xor(rs, 1);
            rs += __shfl_xor(rs, 2);
            rs += __shfl_xor(rs, 4);
            rs += __shfl_xor(rs, 8);
            l_run[r] = alpha[r] * l_run[r] + rs;
            m_run[r] = mnew;
            Ps[w][quad * 4 + r][l16]      = f2bf(p0);
            Ps[w][quad * 4 + r][l16 + 16] = f2bf(p1);
        }

#pragma unroll
        for (int dt = 0; dt < 8; ++dt)
#pragma unroll
            for (int r = 0; r < 4; ++r) O[dt][r] *= alpha[r];

        // PV
        bf8_t pf = *(const bf8_t*)&Ps[w][l16][quad * 8];
#pragma unroll
        for (int dt = 0; dt < 8; ++dt) {
            int d = dt * 16 + l16;
            int ci = d * 4 + (quad ^ (d & 3));
            bf8_t vf = *(const bf8_t*)&Vs[ci * 8];
            O[dt] = __builtin_amdgcn_mfma_f32_16x16x32_bf16(pf, vf, O[dt], 0, 0, 0);
        }
    }

    float inv_l[4];
#pragma unroll
    for (int r = 0; r < 4; ++r) inv_l[r] = 1.0f / l_run[r];
    short* cbase = ctx + (size_t)(b * SEQ + q0 + w * 16 + quad * 4) * HIDN
                       + h * DHD + l16;
#pragma unroll
    for (int r = 0; r < 4; ++r)
#pragma unroll
        for (int dt = 0; dt < 8; ++dt)
            cbase[(size_t)r * HIDN + dt * 16] = f2bf(O[dt][r] * inv_l[r]);
}

// ---------------------------------------------------------------------------
extern "C" void kernel_launch(void* const* d_in, const int* in_sizes, int n_in,
                              void* d_out, int out_size, void* d_ws, size_t ws_size,
                              hipStream_t stream)
{
    const float* x        = (const float*)d_in[0];
    const float* Wq_down  = (const float*)d_in[1];
    const float* Wq_up    = (const float*)d_in[2];
    const float* Wq_rope  = (const float*)d_in[3];
    const float* Wkv_down = (const float*)d_in[4];
    const float* Wk_up    = (const float*)d_in[5];
    const float* Wk_rope  = (const float*)d_in[6];
    const float* Wv_up    = (const float*)d_in[7];
    const float* Wo       = (const float*)d_in[8];
    const float* bo       = (const float*)d_in[9];
    float* out = (float*)d_out;

    // workspace (bf16 shorts)
    short* ws    = (short*)d_ws;
    short* xb    = ws;                 //  8388608
    short* wqd   = ws + 8388608;       //  1048576
    short* wqu   = ws + 9437184;       //   786432
    short* wqr   = ws + 10223616;      //   262144
    short* wkvd  = ws + 10485760;      //  1048576
    short* wku   = ws + 11534336;      //   786432
    short* wkr   = ws + 12320768;      //    65536
    short* wvu   = ws + 12386304;      //  1048576
    short* wob   = ws + 13434880;      //  4194304
    short* qlat  = ws + 17629184;      //  2097152
    short* kvlat = ws + 19726336;      //  2097152
    short* qq    = ws + 21823488;      //  8388608
    short* kk    = ws + 30212096;      //  8388608
    short* vtw   = ws + 38600704;      //  8388608  vT[b][h][d][s]
    short* ctxb  = ws + 46989312;      //  8388608
    short* qrt   = ws + 55377920;      //  2097152
    short* krt   = ws + 57475072;      //   131072  (end 57606144 shorts)

    dim3 blk(256);
    cvt_all<<<dim3(8608), blk, 0, stream>>>(x, Wq_down, Wq_up, Wq_rope, Wkv_down,
                                            Wk_up, Wk_rope, Wv_up, Wo,
                                            xb, wqd, wqu, wqr, wkvd, wku, wkr, wvu, wob);

    gemm_bf16<<<dim3(32,  4), blk, 0, stream>>>(xb,    wqd,  qlat, MTOT,  512, 2048,  512, 0, nullptr);
    gemm_bf16<<<dim3(32,  4), blk, 0, stream>>>(xb,    wkvd, kvlat, MTOT, 512, 2048,  512, 0, nullptr);
    gemm_bf16<<<dim3(32, 12), blk, 0, stream>>>(qlat,  wqu,  qq,   MTOT, 1536,  512, 2048, 1, nullptr);
    gemm_bf16<<<dim3(32,  4), blk, 0, stream>>>(qlat,  wqr,  qrt,  MTOT,  512,  512,  512, 0, nullptr);
    gemm_bf16<<<dim3(32, 12), blk, 0, stream>>>(kvlat, wku,  kk,   MTOT, 1536,  512, 2048, 1, nullptr);
    gemm_bf16<<<dim3(32,  1), blk, 0, stream>>>(xb,    wkr,  krt,  MTOT,   32, 2048,   32, 4, nullptr);
    gemm_bf16<<<dim3(32, 16), blk, 0, stream>>>(kvlat, wvu,  vtw,  MTOT, 2048,  512,    0, 3, nullptr);

    rope_q_kernel<<<dim3(MTOT * NH * RD / 256), blk, 0, stream>>>(qrt, qq);
    rope_k_kernel<<<dim3(MTOT * RD / 256), blk, 0, stream>>>(krt, kk);

    attn_mfma<<<dim3(SEQ / 64, NH, NB), blk, 0, stream>>>(qq, kk, vtw, ctxb);

    gemm_bf16<<<dim3(32, 16), blk, 0, stream>>>(ctxb, wob, out, MTOT, HIDN, HIDN, HIDN, 2, bo);
}

// Round 4
// 564.758 us; speedup vs baseline: 6.5115x; 1.1112x over previous
//
#include <hip/hip_runtime.h>
#include <math.h>

// Problem constants
#define HIDN 2048
#define NH   16
#define LATN 512
#define RD   32
#define DHD  128
#define CDIM 96
#define NB   2
#define SEQ  2048
#define MTOT 4096   // NB*SEQ token rows

typedef __attribute__((ext_vector_type(8))) short bf8_t;   // 8 x bf16 (4 VGPRs)
typedef __attribute__((ext_vector_type(4))) float f4_t;    // MFMA C/D frag
typedef __attribute__((ext_vector_type(4))) short s4_t;    // 4 x bf16 (8 B)

__device__ __forceinline__ short f2bf(float f) {
    union { float f; unsigned u; } x; x.f = f;
    unsigned r = x.u + 0x7fffu + ((x.u >> 16) & 1u);   // round-to-nearest-even
    return (short)(r >> 16);
}
__device__ __forceinline__ float bf2f(short s) {
    union { float f; unsigned u; } x; x.u = ((unsigned)(unsigned short)s) << 16;
    return x.f;
}
// async global->LDS, 16B per lane, lane i lands at ldsbase + i*16
__device__ __forceinline__ void gload16(const void* g, void* l) {
    __builtin_amdgcn_global_load_lds(
        (const __attribute__((address_space(1))) void*)g,
        (__attribute__((address_space(3))) void*)l, 16, 0, 0);
}

// ---------------------------------------------------------------------------
// f32 -> bf16 conversion for x + all 8 weights, one launch.
// ---------------------------------------------------------------------------
__global__ __launch_bounds__(256)
void cvt_all(const float* __restrict__ x,  const float* __restrict__ w0,
             const float* __restrict__ w1, const float* __restrict__ w2,
             const float* __restrict__ w3, const float* __restrict__ w4,
             const float* __restrict__ w5, const float* __restrict__ w6,
             const float* __restrict__ w7,
             short* xb, short* o0, short* o1, short* o2, short* o3,
             short* o4, short* o5, short* o6, short* o7)
{
    int bid = blockIdx.x;
    const float* src; short* dst; int rel;
    if      (bid < 4096) { src = x;  dst = xb; rel = bid; }
    else if (bid < 4608) { src = w0; dst = o0; rel = bid - 4096; }
    else if (bid < 4992) { src = w1; dst = o1; rel = bid - 4608; }
    else if (bid < 5120) { src = w2; dst = o2; rel = bid - 4992; }
    else if (bid < 5632) { src = w3; dst = o3; rel = bid - 5120; }
    else if (bid < 6016) { src = w4; dst = o4; rel = bid - 5632; }
    else if (bid < 6048) { src = w5; dst = o5; rel = bid - 6016; }
    else if (bid < 6560) { src = w6; dst = o6; rel = bid - 6048; }
    else                 { src = w7; dst = o7; rel = bid - 6560; }
    int base = rel * 2048 + threadIdx.x * 8;
    float4 a = *(const float4*)(src + base);
    float4 b = *(const float4*)(src + base + 4);
    s4_t r0 = { f2bf(a.x), f2bf(a.y), f2bf(a.z), f2bf(a.w) };
    s4_t r1 = { f2bf(b.x), f2bf(b.y), f2bf(b.z), f2bf(b.w) };
    *(s4_t*)(dst + base)     = r0;
    *(s4_t*)(dst + base + 4) = r1;
}

// ---------------------------------------------------------------------------
// bf16 MFMA NT GEMM: out[m,col(n)] = sum_k A[m,k]*W[n,k]
// 128x128 tile, BK=32, 4 waves, 4x4 16x16x32 frags. Swizzled gload16 staging.
// modes: 0 bf16 plain (out1, ldc)
//        2 f32 + bias (out1, ldc)
//        4 bf16 plain with N-guard (out1, ldc)
//        5 q-combo:  n<1536 -> head-major scatter into out1 (qh),
//                    n>=1536 -> out2[m][n-1536] (qr raw, ldc 512)
//        6 kv-combo: n<1536 -> head-major scatter into out1 (kh),
//                    n>=1536 -> transposed store into out2 (vT[b][h][d][s])
// ---------------------------------------------------------------------------
__global__ __launch_bounds__(256)
void gemm_bf16(const short* __restrict__ A, const short* __restrict__ W,
               void* __restrict__ out1, void* __restrict__ out2,
               int M, int N, int K, int lda, int ldc,
               int mode, const float* __restrict__ bias)
{
    __shared__ short As[128 * 32];
    __shared__ short Bs[128 * 32];
    const int tid  = threadIdx.x;
    const int w    = tid >> 6;
    const int lane = tid & 63;
    const int l16  = lane & 15;
    const int quad = lane >> 4;
    const int m0 = blockIdx.x * 128;
    const int n0 = blockIdx.y * 128;
    const int wm = (w & 1) * 64;
    const int wn = (w >> 1) * 64;

    int srow[2], skc[2];
#pragma unroll
    for (int j = 0; j < 2; ++j) {
        int c = (w * 32 + j * 16) * 4 + lane;
        srow[j] = c >> 2;
        skc[j]  = (c & 3) ^ (srow[j] & 3);
    }
    const int xq = quad ^ (l16 & 3);

    f4_t acc[4][4];
#pragma unroll
    for (int i = 0; i < 4; ++i)
#pragma unroll
        for (int j = 0; j < 4; ++j) acc[i][j] = (f4_t){0.f, 0.f, 0.f, 0.f};

    for (int k0 = 0; k0 < K; k0 += 32) {
        __syncthreads();
#pragma unroll
        for (int j = 0; j < 2; ++j) {
            const short* ga = A + (size_t)(m0 + srow[j]) * lda + k0 + skc[j] * 8;
            gload16(ga, &As[(w * 32 + j * 16) * 32]);
            int gn = n0 + srow[j]; if (gn >= N) gn = N - 1;
            const short* gb = W + (size_t)gn * K + k0 + skc[j] * 8;
            gload16(gb, &Bs[(w * 32 + j * 16) * 32]);
        }
        __syncthreads();
        bf8_t af[4], bfr[4];
#pragma unroll
        for (int i = 0; i < 4; ++i)
            af[i] = *(const bf8_t*)&As[((wm + i * 16 + l16) * 4 + xq) * 8];
#pragma unroll
        for (int j = 0; j < 4; ++j)
            bfr[j] = *(const bf8_t*)&Bs[((wn + j * 16 + l16) * 4 + xq) * 8];
#pragma unroll
        for (int i = 0; i < 4; ++i)
#pragma unroll
            for (int j = 0; j < 4; ++j)
                acc[i][j] = __builtin_amdgcn_mfma_f32_16x16x32_bf16(
                    af[i], bfr[j], acc[i][j], 0, 0, 0);
    }

    // epilogue (C layout: col = l16, row = quad*4 + r)
#pragma unroll
    for (int mi = 0; mi < 4; ++mi) {
#pragma unroll
        for (int nj = 0; nj < 4; ++nj) {
            const int gm = m0 + wm + mi * 16 + quad * 4;
            const int gn = n0 + wn + nj * 16 + l16;
            const int bb = gm >> 11, ss = gm & 2047;
            if (mode == 0) {
                short* o = (short*)out1 + (size_t)gm * ldc + gn;
#pragma unroll
                for (int r = 0; r < 4; ++r) o[(size_t)r * ldc] = f2bf(acc[mi][nj][r]);
            } else if (mode == 2) {
                float* o = (float*)out1 + (size_t)gm * ldc + gn;
                float bv = bias[gn];
#pragma unroll
                for (int r = 0; r < 4; ++r) o[(size_t)r * ldc] = acc[mi][nj][r] + bv;
            } else if (mode == 4) {
                if (gn < N) {
                    short* o = (short*)out1 + (size_t)gm * ldc + gn;
#pragma unroll
                    for (int r = 0; r < 4; ++r) o[(size_t)r * ldc] = f2bf(acc[mi][nj][r]);
                }
            } else if (mode == 5) {
                if (gn < 1536) {
                    int hh = gn / CDIM, cc = gn % CDIM;
                    short* o = (short*)out1 +
                        (((size_t)(bb * NH + hh) * SEQ + ss) * DHD + cc);
#pragma unroll
                    for (int r = 0; r < 4; ++r) o[(size_t)r * DHD] = f2bf(acc[mi][nj][r]);
                } else {
                    short* o = (short*)out2 + (size_t)gm * 512 + (gn - 1536);
#pragma unroll
                    for (int r = 0; r < 4; ++r) o[(size_t)r * 512] = f2bf(acc[mi][nj][r]);
                }
            } else { // mode 6
                if (gn < 1536) {
                    int hh = gn / CDIM, cc = gn % CDIM;
                    short* o = (short*)out1 +
                        (((size_t)(bb * NH + hh) * SEQ + ss) * DHD + cc);
#pragma unroll
                    for (int r = 0; r < 4; ++r) o[(size_t)r * DHD] = f2bf(acc[mi][nj][r]);
                } else {
                    int n2 = gn - 1536;
                    int h2 = n2 >> 7, dh = n2 & 127;
                    size_t idx = ((size_t)(bb * NH + h2) * DHD + dh) * SEQ + ss;
                    s4_t pk = { f2bf(acc[mi][nj][0]), f2bf(acc[mi][nj][1]),
                                f2bf(acc[mi][nj][2]), f2bf(acc[mi][nj][3]) };
                    *(s4_t*)((short*)out2 + idx) = pk;
                }
            }
        }
    }
}

// ---------------------------------------------------------------------------
// RoPE (bf16), head-major outputs [b][h][s][128]
// ---------------------------------------------------------------------------
__global__ void rope_q_kernel(const short* __restrict__ qr, short* __restrict__ qh)
{
    int idx = blockIdx.x * blockDim.x + threadIdx.x;
    int m = idx >> 9;
    int h = (idx >> 5) & 15;
    int r = idx & 31;
    int b = m >> 11, s = m & (SEQ - 1);
    float invf = expf(-((float)(2 * (r & 15)) / 32.0f) * 9.210340371976184f);
    float f = (float)s * invf;
    float cs = cosf(f), sn = sinf(f);
    float val = bf2f(qr[(size_t)m * 512 + h * 32 + r]);
    float partner = bf2f(qr[(size_t)m * 512 + h * 32 + (r ^ 16)]);
    float rot = (r < 16) ? -partner : partner;
    qh[((size_t)(b * NH + h) * SEQ + s) * DHD + CDIM + r] = f2bf(val * cs + rot * sn);
}

__global__ void rope_k_kernel(const short* __restrict__ kr, short* __restrict__ kh)
{
    int idx = blockIdx.x * blockDim.x + threadIdx.x;
    int m = idx >> 5;
    int r = idx & 31;
    int b = m >> 11, s = m & (SEQ - 1);
    float invf = expf(-((float)(2 * (r & 15)) / 32.0f) * 9.210340371976184f);
    float f = (float)s * invf;
    float cs = cosf(f), sn = sinf(f);
    float val = bf2f(kr[(size_t)m * 32 + r]);
    float partner = bf2f(kr[(size_t)m * 32 + (r ^ 16)]);
    float rot = (r < 16) ? -partner : partner;
    short o = f2bf(val * cs + rot * sn);
    short* dst = kh + ((size_t)b * NH * SEQ + s) * DHD + CDIM + r;
#pragma unroll
    for (int h = 0; h < NH; ++h) dst[(size_t)h * SEQ * DHD] = o;
}

// ---------------------------------------------------------------------------
// MFMA flash attention v2: double-buffered gload16 prefetch, 1 barrier/tile.
// BQ=64 (16 rows/wave), BK=32. K head-major [b][h][s][128]; V pre-transposed
// [b][h][d][s]. Swizzled LDS chunk layouts (<=2-way conflicts, free):
//   K slot s: key=s>>4, dch=(s&15)^(key&15)
//   V slot s: d=s>>2,  kc=(s&3)^((d>>1)&3)
// Q frags pre-scaled by 1/sqrt(D). LDS = 2*8K + 2*8K + Ps 5K = 37 KB.
// ---------------------------------------------------------------------------
__global__ __launch_bounds__(256)
void attn_mfma(const short* __restrict__ qh, const short* __restrict__ kh,
               const short* __restrict__ vt, short* __restrict__ ctx)
{
    const int qb = blockIdx.x, h = blockIdx.y, b = blockIdx.z;
    const int q0 = qb * 64;
    __shared__ short Ks[2][4096];
    __shared__ short Vs[2][4096];
    __shared__ short Ps[4][16][40];
    const int tid  = threadIdx.x;
    const int w    = tid >> 6;
    const int lane = tid & 63;
    const int l16  = lane & 15;
    const int quad = lane >> 4;
    const float scale = 0.08838834764831845f;  // 1/sqrt(128)

    const short* khead = kh + (size_t)(b * NH + h) * SEQ * DHD;
    const short* vhead = vt + (size_t)(b * NH + h) * DHD * SEQ;

    // per-thread staging offsets (2 chunks each for K and V)
    int koff[2], voff[2], ldso[2];
#pragma unroll
    for (int j = 0; j < 2; ++j) {
        int s = j * 256 + tid;
        int key = s >> 4, dch = (s & 15) ^ (key & 15);
        koff[j] = key * DHD + dch * 8;
        int d = s >> 2, kc = (s & 3) ^ ((d >> 1) & 3);
        voff[j] = d * SEQ + kc * 8;
        ldso[j] = (j * 256 + w * 64) * 8;
    }

    // Q A-frags, pre-scaled
    bf8_t qf[4];
    {
        const short* qp = qh + ((size_t)(b * NH + h) * SEQ + q0 + w * 16 + l16) * DHD
                             + quad * 8;
#pragma unroll
        for (int ks = 0; ks < 4; ++ks) {
            bf8_t raw = *(const bf8_t*)(qp + ks * 32);
#pragma unroll
            for (int j = 0; j < 8; ++j) qf[ks][j] = f2bf(bf2f(raw[j]) * scale);
        }
    }

    f4_t O[8];
#pragma unroll
    for (int i = 0; i < 8; ++i) O[i] = (f4_t){0.f, 0.f, 0.f, 0.f};
    float m_run[4], l_run[4];
#pragma unroll
    for (int r = 0; r < 4; ++r) { m_run[r] = -3e38f; l_run[r] = 0.f; }

    const int ntiles = 2 * qb + 2;
    // prestage tile 0 into buffer 0
#pragma unroll
    for (int j = 0; j < 2; ++j) {
        gload16(khead + koff[j], &Ks[0][ldso[j]]);
        gload16(vhead + voff[j], &Vs[0][ldso[j]]);
    }

    for (int t = 0; t < ntiles; ++t) {
        const int cur = t & 1;
        const int c0 = t * 32;
        __syncthreads();   // drains vmcnt: buf[cur] ready; buf[cur^1] free
        if (t + 1 < ntiles) {
            const short* kt = khead + (size_t)(c0 + 32) * DHD;
#pragma unroll
            for (int j = 0; j < 2; ++j) {
                gload16(kt + koff[j], &Ks[cur ^ 1][ldso[j]]);
                gload16(vhead + voff[j] + c0 + 32, &Vs[cur ^ 1][ldso[j]]);
            }
        }

        // S = Q K^T (scores already scaled via Q)
        f4_t S0 = {0.f, 0.f, 0.f, 0.f}, S1 = {0.f, 0.f, 0.f, 0.f};
#pragma unroll
        for (int ks = 0; ks < 4; ++ks) {
            int dch = ks * 4 + quad;
            int si0 = l16 * 16 + (dch ^ l16);
            int si1 = (l16 + 16) * 16 + (dch ^ l16);
            bf8_t b0 = *(const bf8_t*)&Ks[cur][si0 * 8];
            bf8_t b1 = *(const bf8_t*)&Ks[cur][si1 * 8];
            S0 = __builtin_amdgcn_mfma_f32_16x16x32_bf16(qf[ks], b0, S0, 0, 0, 0);
            S1 = __builtin_amdgcn_mfma_f32_16x16x32_bf16(qf[ks], b1, S1, 0, 0, 0);
        }

        // causal mask + online softmax (C layout: row=quad*4+r, col=l16/l16+16)
        const int grow0 = q0 + w * 16 + quad * 4;
        float alpha[4];
#pragma unroll
        for (int r = 0; r < 4; ++r) {
            const int grow = grow0 + r;
            float s0 = (c0 + l16      <= grow) ? S0[r] : -3e38f;
            float s1 = (c0 + l16 + 16 <= grow) ? S1[r] : -3e38f;
            float mx = fmaxf(s0, s1);
            mx = fmaxf(mx, __shfl_xor(mx, 1));
            mx = fmaxf(mx, __shfl_xor(mx, 2));
            mx = fmaxf(mx, __shfl_xor(mx, 4));
            mx = fmaxf(mx, __shfl_xor(mx, 8));
            const float mnew = fmaxf(m_run[r], mx);
            alpha[r] = __expf(m_run[r] - mnew);
            const float p0 = __expf(s0 - mnew);
            const float p1 = __expf(s1 - mnew);
            float rs = p0 + p1;
            rs += __shfl_xor(rs, 1);
            rs += __shfl_xor(rs, 2);
            rs += __shfl_xor(rs, 4);
            rs += __shfl_xor(rs, 8);
            l_run[r] = alpha[r] * l_run[r] + rs;
            m_run[r] = mnew;
            Ps[w][quad * 4 + r][l16]      = f2bf(p0);
            Ps[w][quad * 4 + r][l16 + 16] = f2bf(p1);
        }

#pragma unroll
        for (int dt = 0; dt < 8; ++dt)
#pragma unroll
            for (int r = 0; r < 4; ++r) O[dt][r] *= alpha[r];

        // PV
        bf8_t pf = *(const bf8_t*)&Ps[w][l16][quad * 8];
#pragma unroll
        for (int dt = 0; dt < 8; ++dt) {
            int d = dt * 16 + l16;
            int si = d * 4 + (quad ^ ((d >> 1) & 3));
            bf8_t vf = *(const bf8_t*)&Vs[cur][si * 8];
            O[dt] = __builtin_amdgcn_mfma_f32_16x16x32_bf16(pf, vf, O[dt], 0, 0, 0);
        }
    }

    float inv_l[4];
#pragma unroll
    for (int r = 0; r < 4; ++r) inv_l[r] = 1.0f / l_run[r];
    short* cbase = ctx + (size_t)(b * SEQ + q0 + w * 16 + quad * 4) * HIDN
                       + h * DHD + l16;
#pragma unroll
    for (int r = 0; r < 4; ++r)
#pragma unroll
        for (int dt = 0; dt < 8; ++dt)
            cbase[(size_t)r * HIDN + dt * 16] = f2bf(O[dt][r] * inv_l[r]);
}

// ---------------------------------------------------------------------------
extern "C" void kernel_launch(void* const* d_in, const int* in_sizes, int n_in,
                              void* d_out, int out_size, void* d_ws, size_t ws_size,
                              hipStream_t stream)
{
    const float* x        = (const float*)d_in[0];
    const float* Wq_down  = (const float*)d_in[1];
    const float* Wq_up    = (const float*)d_in[2];
    const float* Wq_rope  = (const float*)d_in[3];
    const float* Wkv_down = (const float*)d_in[4];
    const float* Wk_up    = (const float*)d_in[5];
    const float* Wk_rope  = (const float*)d_in[6];
    const float* Wv_up    = (const float*)d_in[7];
    const float* Wo       = (const float*)d_in[8];
    const float* bo       = (const float*)d_in[9];
    float* out = (float*)d_out;

    // workspace (bf16 shorts)
    short* ws     = (short*)d_ws;
    short* xb     = ws;                 //  8388608
    short* wdown  = ws + 8388608;       //  2097152  [Wq_down | Wkv_down]
    short* wqur   = ws + 10485760;      //  1048576  [Wq_up | Wq_rope]
    short* wkvu   = ws + 11534336;      //  1835008  [Wk_up | Wv_up]
    short* wkr    = ws + 13369344;      //    65536
    short* wob    = ws + 13434880;      //  4194304
    short* qkvlat = ws + 17629184;      //  4194304  [4096][1024] = qlat|kvlat
    short* qhb    = ws + 21823488;      //  8388608  [b][h][s][128]
    short* khb    = ws + 30212096;      //  8388608  [b][h][s][128]
    short* vtw    = ws + 38600704;      //  8388608  [b][h][d][s]
    short* ctxb   = ws + 46989312;      //  8388608  [b][s][2048]
    short* qrt    = ws + 55377920;      //  2097152
    short* krt    = ws + 57475072;      //   131072

    dim3 blk(256);
    cvt_all<<<dim3(8608), blk, 0, stream>>>(
        x, Wq_down, Wq_up, Wq_rope, Wkv_down, Wk_up, Wk_rope, Wv_up, Wo,
        xb, wdown, wqur, wqur + 786432, wdown + 1048576,
        wkvu, wkr, wkvu + 786432, wob);

    // down-combo: [q_lat | kv_lat]
    gemm_bf16<<<dim3(32,  8), blk, 0, stream>>>(xb, wdown, qkvlat, nullptr,
                                                MTOT, 1024, 2048, 2048, 1024, 0, nullptr);
    // q-combo: content -> qh (head-major), rope-raw -> qrt
    gemm_bf16<<<dim3(32, 16), blk, 0, stream>>>(qkvlat, wqur, qhb, qrt,
                                                MTOT, 2048, 512, 1024, 0, 5, nullptr);
    // kv-combo: k content -> kh, v -> vT
    gemm_bf16<<<dim3(32, 28), blk, 0, stream>>>(qkvlat + 512, wkvu, khb, vtw,
                                                MTOT, 3584, 512, 1024, 0, 6, nullptr);
    // k rope raw
    gemm_bf16<<<dim3(32,  1), blk, 0, stream>>>(xb, wkr, krt, nullptr,
                                                MTOT, 32, 2048, 2048, 32, 4, nullptr);

    rope_q_kernel<<<dim3(MTOT * NH * RD / 256), blk, 0, stream>>>(qrt, qhb);
    rope_k_kernel<<<dim3(MTOT * RD / 256), blk, 0, stream>>>(krt, khb);

    attn_mfma<<<dim3(SEQ / 64, NH, NB), blk, 0, stream>>>(qhb, khb, vtw, ctxb);

    gemm_bf16<<<dim3(32, 16), blk, 0, stream>>>(ctxb, wob, out, nullptr,
                                                MTOT, 2048, 2048, 2048, 2048, 2, bo);
}

// Round 5
// 464.638 us; speedup vs baseline: 7.9146x; 1.2155x over previous
//
#include <hip/hip_runtime.h>
#include <math.h>

// Problem constants
#define HIDN 2048
#define NH   16
#define LATN 512
#define RD   32
#define DHD  128
#define CDIM 96
#define NB   2
#define SEQ  2048
#define MTOT 4096   // NB*SEQ token rows

typedef __attribute__((ext_vector_type(8))) short bf8_t;   // 8 x bf16 (4 VGPRs)
typedef __attribute__((ext_vector_type(4))) float f4_t;    // MFMA C/D frag
typedef __attribute__((ext_vector_type(4))) short s4_t;    // 4 x bf16 (8 B)

__device__ __forceinline__ short f2bf(float f) {
    union { float f; unsigned u; } x; x.f = f;
    unsigned r = x.u + 0x7fffu + ((x.u >> 16) & 1u);   // round-to-nearest-even
    return (short)(r >> 16);
}
__device__ __forceinline__ float bf2f(short s) {
    union { float f; unsigned u; } x; x.u = ((unsigned)(unsigned short)s) << 16;
    return x.f;
}
// async global->LDS, 16B per lane, lane i lands at ldsbase + i*16
__device__ __forceinline__ void gload16(const void* g, void* l) {
    __builtin_amdgcn_global_load_lds(
        (const __attribute__((address_space(1))) void*)g,
        (__attribute__((address_space(3))) void*)l, 16, 0, 0);
}

// ---------------------------------------------------------------------------
// f32 -> bf16 conversion for x + all 8 weights, one launch.
// ---------------------------------------------------------------------------
__global__ __launch_bounds__(256)
void cvt_all(const float* __restrict__ x,  const float* __restrict__ w0,
             const float* __restrict__ w1, const float* __restrict__ w2,
             const float* __restrict__ w3, const float* __restrict__ w4,
             const float* __restrict__ w5, const float* __restrict__ w6,
             const float* __restrict__ w7,
             short* xb, short* o0, short* o1, short* o2, short* o3,
             short* o4, short* o5, short* o6, short* o7)
{
    int bid = blockIdx.x;
    const float* src; short* dst; int rel;
    if      (bid < 4096) { src = x;  dst = xb; rel = bid; }
    else if (bid < 4608) { src = w0; dst = o0; rel = bid - 4096; }
    else if (bid < 4992) { src = w1; dst = o1; rel = bid - 4608; }
    else if (bid < 5120) { src = w2; dst = o2; rel = bid - 4992; }
    else if (bid < 5632) { src = w3; dst = o3; rel = bid - 5120; }
    else if (bid < 6016) { src = w4; dst = o4; rel = bid - 5632; }
    else if (bid < 6048) { src = w5; dst = o5; rel = bid - 6016; }
    else if (bid < 6560) { src = w6; dst = o6; rel = bid - 6048; }
    else                 { src = w7; dst = o7; rel = bid - 6560; }
    int base = rel * 2048 + threadIdx.x * 8;
    float4 a = *(const float4*)(src + base);
    float4 b = *(const float4*)(src + base + 4);
    s4_t r0 = { f2bf(a.x), f2bf(a.y), f2bf(a.z), f2bf(a.w) };
    s4_t r1 = { f2bf(b.x), f2bf(b.y), f2bf(b.z), f2bf(b.w) };
    *(s4_t*)(dst + base)     = r0;
    *(s4_t*)(dst + base + 4) = r1;
}

// ---------------------------------------------------------------------------
// bf16 MFMA NT GEMM: out[m,col(n)] = sum_k A[m,k]*W[n,k]
// 128x128 tile, BK=32, 4 waves, 4x4 16x16x32 frags. Swizzled gload16 staging.
// modes: 0 bf16 plain | 2 f32+bias | 4 bf16 N-guard
//        5 q-combo (content->head-major out1, rope-raw->out2)
//        6 kv-combo (k content->head-major out1, v->transposed out2)
// ---------------------------------------------------------------------------
__global__ __launch_bounds__(256)
void gemm_bf16(const short* __restrict__ A, const short* __restrict__ W,
               void* __restrict__ out1, void* __restrict__ out2,
               int M, int N, int K, int lda, int ldc,
               int mode, const float* __restrict__ bias)
{
    __shared__ short As[128 * 32];
    __shared__ short Bs[128 * 32];
    const int tid  = threadIdx.x;
    const int w    = tid >> 6;
    const int lane = tid & 63;
    const int l16  = lane & 15;
    const int quad = lane >> 4;
    const int m0 = blockIdx.x * 128;
    const int n0 = blockIdx.y * 128;
    const int wm = (w & 1) * 64;
    const int wn = (w >> 1) * 64;

    int srow[2], skc[2];
#pragma unroll
    for (int j = 0; j < 2; ++j) {
        int c = (w * 32 + j * 16) * 4 + lane;
        srow[j] = c >> 2;
        skc[j]  = (c & 3) ^ (srow[j] & 3);
    }
    const int xq = quad ^ (l16 & 3);

    f4_t acc[4][4];
#pragma unroll
    for (int i = 0; i < 4; ++i)
#pragma unroll
        for (int j = 0; j < 4; ++j) acc[i][j] = (f4_t){0.f, 0.f, 0.f, 0.f};

    for (int k0 = 0; k0 < K; k0 += 32) {
        __syncthreads();
#pragma unroll
        for (int j = 0; j < 2; ++j) {
            const short* ga = A + (size_t)(m0 + srow[j]) * lda + k0 + skc[j] * 8;
            gload16(ga, &As[(w * 32 + j * 16) * 32]);
            int gn = n0 + srow[j]; if (gn >= N) gn = N - 1;
            const short* gb = W + (size_t)gn * K + k0 + skc[j] * 8;
            gload16(gb, &Bs[(w * 32 + j * 16) * 32]);
        }
        __syncthreads();
        bf8_t af[4], bfr[4];
#pragma unroll
        for (int i = 0; i < 4; ++i)
            af[i] = *(const bf8_t*)&As[((wm + i * 16 + l16) * 4 + xq) * 8];
#pragma unroll
        for (int j = 0; j < 4; ++j)
            bfr[j] = *(const bf8_t*)&Bs[((wn + j * 16 + l16) * 4 + xq) * 8];
#pragma unroll
        for (int i = 0; i < 4; ++i)
#pragma unroll
            for (int j = 0; j < 4; ++j)
                acc[i][j] = __builtin_amdgcn_mfma_f32_16x16x32_bf16(
                    af[i], bfr[j], acc[i][j], 0, 0, 0);
    }

    // epilogue (C layout: col = l16, row = quad*4 + r)
#pragma unroll
    for (int mi = 0; mi < 4; ++mi) {
#pragma unroll
        for (int nj = 0; nj < 4; ++nj) {
            const int gm = m0 + wm + mi * 16 + quad * 4;
            const int gn = n0 + wn + nj * 16 + l16;
            const int bb = gm >> 11, ss = gm & 2047;
            if (mode == 0) {
                short* o = (short*)out1 + (size_t)gm * ldc + gn;
#pragma unroll
                for (int r = 0; r < 4; ++r) o[(size_t)r * ldc] = f2bf(acc[mi][nj][r]);
            } else if (mode == 2) {
                float* o = (float*)out1 + (size_t)gm * ldc + gn;
                float bv = bias[gn];
#pragma unroll
                for (int r = 0; r < 4; ++r) o[(size_t)r * ldc] = acc[mi][nj][r] + bv;
            } else if (mode == 4) {
                if (gn < N) {
                    short* o = (short*)out1 + (size_t)gm * ldc + gn;
#pragma unroll
                    for (int r = 0; r < 4; ++r) o[(size_t)r * ldc] = f2bf(acc[mi][nj][r]);
                }
            } else if (mode == 5) {
                if (gn < 1536) {
                    int hh = gn / CDIM, cc = gn % CDIM;
                    short* o = (short*)out1 +
                        (((size_t)(bb * NH + hh) * SEQ + ss) * DHD + cc);
#pragma unroll
                    for (int r = 0; r < 4; ++r) o[(size_t)r * DHD] = f2bf(acc[mi][nj][r]);
                } else {
                    short* o = (short*)out2 + (size_t)gm * 512 + (gn - 1536);
#pragma unroll
                    for (int r = 0; r < 4; ++r) o[(size_t)r * 512] = f2bf(acc[mi][nj][r]);
                }
            } else { // mode 6
                if (gn < 1536) {
                    int hh = gn / CDIM, cc = gn % CDIM;
                    short* o = (short*)out1 +
                        (((size_t)(bb * NH + hh) * SEQ + ss) * DHD + cc);
#pragma unroll
                    for (int r = 0; r < 4; ++r) o[(size_t)r * DHD] = f2bf(acc[mi][nj][r]);
                } else {
                    int n2 = gn - 1536;
                    int h2 = n2 >> 7, dh = n2 & 127;
                    size_t idx = ((size_t)(bb * NH + h2) * DHD + dh) * SEQ + ss;
                    s4_t pk = { f2bf(acc[mi][nj][0]), f2bf(acc[mi][nj][1]),
                                f2bf(acc[mi][nj][2]), f2bf(acc[mi][nj][3]) };
                    *(s4_t*)((short*)out2 + idx) = pk;
                }
            }
        }
    }
}

// ---------------------------------------------------------------------------
// RoPE (bf16), head-major outputs [b][h][s][128]
// ---------------------------------------------------------------------------
__global__ void rope_q_kernel(const short* __restrict__ qr, short* __restrict__ qh)
{
    int idx = blockIdx.x * blockDim.x + threadIdx.x;
    int m = idx >> 9;
    int h = (idx >> 5) & 15;
    int r = idx & 31;
    int b = m >> 11, s = m & (SEQ - 1);
    float invf = expf(-((float)(2 * (r & 15)) / 32.0f) * 9.210340371976184f);
    float f = (float)s * invf;
    float cs = cosf(f), sn = sinf(f);
    float val = bf2f(qr[(size_t)m * 512 + h * 32 + r]);
    float partner = bf2f(qr[(size_t)m * 512 + h * 32 + (r ^ 16)]);
    float rot = (r < 16) ? -partner : partner;
    qh[((size_t)(b * NH + h) * SEQ + s) * DHD + CDIM + r] = f2bf(val * cs + rot * sn);
}

__global__ void rope_k_kernel(const short* __restrict__ kr, short* __restrict__ kh)
{
    int idx = blockIdx.x * blockDim.x + threadIdx.x;
    int m = idx >> 5;
    int r = idx & 31;
    int b = m >> 11, s = m & (SEQ - 1);
    float invf = expf(-((float)(2 * (r & 15)) / 32.0f) * 9.210340371976184f);
    float f = (float)s * invf;
    float cs = cosf(f), sn = sinf(f);
    float val = bf2f(kr[(size_t)m * 32 + r]);
    float partner = bf2f(kr[(size_t)m * 32 + (r ^ 16)]);
    float rot = (r < 16) ? -partner : partner;
    short o = f2bf(val * cs + rot * sn);
    short* dst = kh + ((size_t)b * NH * SEQ + s) * DHD + CDIM + r;
#pragma unroll
    for (int h = 0; h < NH; ++h) dst[(size_t)h * SEQ * DHD] = o;
}

// ---------------------------------------------------------------------------
// MFMA flash attention v3: causal load-balanced pairing.
// Each block processes TWO q-tiles: qb = blockIdx.x and 31 - blockIdx.x,
// sequentially -> every block does exactly 68 key-tiles regardless of
// dispatch mapping (fixes the 33x causal imbalance that capped occupancy).
// Per-phase: BQ=64 (16 rows/wave), BK=32, double-buffered gload16 prefetch,
// swizzled LDS chunk layouts (<=2-way conflicts), Q pre-scaled by 1/sqrt(D).
// ---------------------------------------------------------------------------
__global__ __launch_bounds__(256)
void attn_mfma(const short* __restrict__ qh, const short* __restrict__ kh,
               const short* __restrict__ vt, short* __restrict__ ctx)
{
    const int h = blockIdx.y, b = blockIdx.z;
    __shared__ short Ks[2][4096];
    __shared__ short Vs[2][4096];
    __shared__ short Ps[4][16][40];
    const int tid  = threadIdx.x;
    const int w    = tid >> 6;
    const int lane = tid & 63;
    const int l16  = lane & 15;
    const int quad = lane >> 4;
    const float scale = 0.08838834764831845f;  // 1/sqrt(128)

    const short* khead = kh + (size_t)(b * NH + h) * SEQ * DHD;
    const short* vhead = vt + (size_t)(b * NH + h) * DHD * SEQ;

    // per-thread staging offsets (2 chunks each for K and V)
    int koff[2], voff[2], ldso[2];
#pragma unroll
    for (int j = 0; j < 2; ++j) {
        int s = j * 256 + tid;
        int key = s >> 4, dch = (s & 15) ^ (key & 15);
        koff[j] = key * DHD + dch * 8;
        int d = s >> 2, kc = (s & 3) ^ ((d >> 1) & 3);
        voff[j] = d * SEQ + kc * 8;
        ldso[j] = (j * 256 + w * 64) * 8;
    }

    for (int phase = 0; phase < 2; ++phase) {
        const int qb = phase ? (31 - (int)blockIdx.x) : (int)blockIdx.x;
        const int q0 = qb * 64;

        // Q A-frags, pre-scaled
        bf8_t qf[4];
        {
            const short* qp = qh + ((size_t)(b * NH + h) * SEQ + q0 + w * 16 + l16) * DHD
                                 + quad * 8;
#pragma unroll
            for (int ks = 0; ks < 4; ++ks) {
                bf8_t raw = *(const bf8_t*)(qp + ks * 32);
#pragma unroll
                for (int j = 0; j < 8; ++j) qf[ks][j] = f2bf(bf2f(raw[j]) * scale);
            }
        }

        f4_t O[8];
#pragma unroll
        for (int i = 0; i < 8; ++i) O[i] = (f4_t){0.f, 0.f, 0.f, 0.f};
        float m_run[4], l_run[4];
#pragma unroll
        for (int r = 0; r < 4; ++r) { m_run[r] = -3e38f; l_run[r] = 0.f; }

        const int ntiles = 2 * qb + 2;
        __syncthreads();   // previous phase's LDS reads done; safe to restage
        // prestage tile 0 into buffer 0
#pragma unroll
        for (int j = 0; j < 2; ++j) {
            gload16(khead + koff[j], &Ks[0][ldso[j]]);
            gload16(vhead + voff[j], &Vs[0][ldso[j]]);
        }

        for (int t = 0; t < ntiles; ++t) {
            const int cur = t & 1;
            const int c0 = t * 32;
            __syncthreads();   // buf[cur] ready; buf[cur^1] free
            if (t + 1 < ntiles) {
                const short* kt = khead + (size_t)(c0 + 32) * DHD;
#pragma unroll
                for (int j = 0; j < 2; ++j) {
                    gload16(kt + koff[j], &Ks[cur ^ 1][ldso[j]]);
                    gload16(vhead + voff[j] + c0 + 32, &Vs[cur ^ 1][ldso[j]]);
                }
            }

            // S = Q K^T (scores pre-scaled via Q)
            f4_t S0 = {0.f, 0.f, 0.f, 0.f}, S1 = {0.f, 0.f, 0.f, 0.f};
#pragma unroll
            for (int ks = 0; ks < 4; ++ks) {
                int dch = ks * 4 + quad;
                int si0 = l16 * 16 + (dch ^ l16);
                int si1 = (l16 + 16) * 16 + (dch ^ l16);
                bf8_t b0 = *(const bf8_t*)&Ks[cur][si0 * 8];
                bf8_t b1 = *(const bf8_t*)&Ks[cur][si1 * 8];
                S0 = __builtin_amdgcn_mfma_f32_16x16x32_bf16(qf[ks], b0, S0, 0, 0, 0);
                S1 = __builtin_amdgcn_mfma_f32_16x16x32_bf16(qf[ks], b1, S1, 0, 0, 0);
            }

            // causal mask + online softmax (C layout: row=quad*4+r, col=l16/l16+16)
            const int grow0 = q0 + w * 16 + quad * 4;
            float alpha[4];
#pragma unroll
            for (int r = 0; r < 4; ++r) {
                const int grow = grow0 + r;
                float s0 = (c0 + l16      <= grow) ? S0[r] : -3e38f;
                float s1 = (c0 + l16 + 16 <= grow) ? S1[r] : -3e38f;
                float mx = fmaxf(s0, s1);
                mx = fmaxf(mx, __shfl_xor(mx, 1));
                mx = fmaxf(mx, __shfl_xor(mx, 2));
                mx = fmaxf(mx, __shfl_xor(mx, 4));
                mx = fmaxf(mx, __shfl_xor(mx, 8));
                const float mnew = fmaxf(m_run[r], mx);
                alpha[r] = __expf(m_run[r] - mnew);
                const float p0 = __expf(s0 - mnew);
                const float p1 = __expf(s1 - mnew);
                float rs = p0 + p1;
                rs += __shfl_xor(rs, 1);
                rs += __shfl_xor(rs, 2);
                rs += __shfl_xor(rs, 4);
                rs += __shfl_xor(rs, 8);
                l_run[r] = alpha[r] * l_run[r] + rs;
                m_run[r] = mnew;
                Ps[w][quad * 4 + r][l16]      = f2bf(p0);
                Ps[w][quad * 4 + r][l16 + 16] = f2bf(p1);
            }

#pragma unroll
            for (int dt = 0; dt < 8; ++dt)
#pragma unroll
                for (int r = 0; r < 4; ++r) O[dt][r] *= alpha[r];

            // PV
            bf8_t pf = *(const bf8_t*)&Ps[w][l16][quad * 8];
#pragma unroll
            for (int dt = 0; dt < 8; ++dt) {
                int d = dt * 16 + l16;
                int si = d * 4 + (quad ^ ((d >> 1) & 3));
                bf8_t vf = *(const bf8_t*)&Vs[cur][si * 8];
                O[dt] = __builtin_amdgcn_mfma_f32_16x16x32_bf16(pf, vf, O[dt], 0, 0, 0);
            }
        }

        float inv_l[4];
#pragma unroll
        for (int r = 0; r < 4; ++r) inv_l[r] = 1.0f / l_run[r];
        short* cbase = ctx + (size_t)(b * SEQ + q0 + w * 16 + quad * 4) * HIDN
                           + h * DHD + l16;
#pragma unroll
        for (int r = 0; r < 4; ++r)
#pragma unroll
            for (int dt = 0; dt < 8; ++dt)
                cbase[(size_t)r * HIDN + dt * 16] = f2bf(O[dt][r] * inv_l[r]);
    }
}

// ---------------------------------------------------------------------------
extern "C" void kernel_launch(void* const* d_in, const int* in_sizes, int n_in,
                              void* d_out, int out_size, void* d_ws, size_t ws_size,
                              hipStream_t stream)
{
    const float* x        = (const float*)d_in[0];
    const float* Wq_down  = (const float*)d_in[1];
    const float* Wq_up    = (const float*)d_in[2];
    const float* Wq_rope  = (const float*)d_in[3];
    const float* Wkv_down = (const float*)d_in[4];
    const float* Wk_up    = (const float*)d_in[5];
    const float* Wk_rope  = (const float*)d_in[6];
    const float* Wv_up    = (const float*)d_in[7];
    const float* Wo       = (const float*)d_in[8];
    const float* bo       = (const float*)d_in[9];
    float* out = (float*)d_out;

    // workspace (bf16 shorts)
    short* ws     = (short*)d_ws;
    short* xb     = ws;                 //  8388608
    short* wdown  = ws + 8388608;       //  2097152  [Wq_down | Wkv_down]
    short* wqur   = ws + 10485760;      //  1048576  [Wq_up | Wq_rope]
    short* wkvu   = ws + 11534336;      //  1835008  [Wk_up | Wv_up]
    short* wkr    = ws + 13369344;      //    65536
    short* wob    = ws + 13434880;      //  4194304
    short* qkvlat = ws + 17629184;      //  4194304  [4096][1024] = qlat|kvlat
    short* qhb    = ws + 21823488;      //  8388608  [b][h][s][128]
    short* khb    = ws + 30212096;      //  8388608  [b][h][s][128]
    short* vtw    = ws + 38600704;      //  8388608  [b][h][d][s]
    short* ctxb   = ws + 46989312;      //  8388608  [b][s][2048]
    short* qrt    = ws + 55377920;      //  2097152
    short* krt    = ws + 57475072;      //   131072

    dim3 blk(256);
    cvt_all<<<dim3(8608), blk, 0, stream>>>(
        x, Wq_down, Wq_up, Wq_rope, Wkv_down, Wk_up, Wk_rope, Wv_up, Wo,
        xb, wdown, wqur, wqur + 786432, wdown + 1048576,
        wkvu, wkr, wkvu + 786432, wob);

    // down-combo: [q_lat | kv_lat]
    gemm_bf16<<<dim3(32,  8), blk, 0, stream>>>(xb, wdown, qkvlat, nullptr,
                                                MTOT, 1024, 2048, 2048, 1024, 0, nullptr);
    // q-combo: content -> qh (head-major), rope-raw -> qrt
    gemm_bf16<<<dim3(32, 16), blk, 0, stream>>>(qkvlat, wqur, qhb, qrt,
                                                MTOT, 2048, 512, 1024, 0, 5, nullptr);
    // kv-combo: k content -> kh, v -> vT
    gemm_bf16<<<dim3(32, 28), blk, 0, stream>>>(qkvlat + 512, wkvu, khb, vtw,
                                                MTOT, 3584, 512, 1024, 0, 6, nullptr);
    // k rope raw
    gemm_bf16<<<dim3(32,  1), blk, 0, stream>>>(xb, wkr, krt, nullptr,
                                                MTOT, 32, 2048, 2048, 32, 4, nullptr);

    rope_q_kernel<<<dim3(MTOT * NH * RD / 256), blk, 0, stream>>>(qrt, qhb);
    rope_k_kernel<<<dim3(MTOT * RD / 256), blk, 0, stream>>>(krt, khb);

    attn_mfma<<<dim3(16, NH, NB), blk, 0, stream>>>(qhb, khb, vtw, ctxb);

    gemm_bf16<<<dim3(32, 16), blk, 0, stream>>>(ctxb, wob, out, nullptr,
                                                MTOT, 2048, 2048, 2048, 2048, 2, bo);
}

// Round 6
// 403.285 us; speedup vs baseline: 9.1186x; 1.1521x over previous
//
#include <hip/hip_runtime.h>
#include <math.h>

// Problem constants
#define HIDN 2048
#define NH   16
#define LATN 512
#define RD   32
#define DHD  128
#define CDIM 96
#define NB   2
#define SEQ  2048
#define MTOT 4096   // NB*SEQ token rows

typedef __attribute__((ext_vector_type(8))) short bf8_t;   // 8 x bf16 (4 VGPRs)
typedef __attribute__((ext_vector_type(4))) float f4_t;    // MFMA C/D frag
typedef __attribute__((ext_vector_type(4))) short s4_t;    // 4 x bf16 (8 B)

__device__ __forceinline__ short f2bf(float f) {
    union { float f; unsigned u; } x; x.f = f;
    unsigned r = x.u + 0x7fffu + ((x.u >> 16) & 1u);   // round-to-nearest-even
    return (short)(r >> 16);
}
__device__ __forceinline__ float bf2f(short s) {
    union { float f; unsigned u; } x; x.u = ((unsigned)(unsigned short)s) << 16;
    return x.f;
}
// async global->LDS, 16B per lane, lane i lands at ldsbase + i*16
__device__ __forceinline__ void gload16(const void* g, void* l) {
    __builtin_amdgcn_global_load_lds(
        (const __attribute__((address_space(1))) void*)g,
        (__attribute__((address_space(3))) void*)l, 16, 0, 0);
}

// ---------------------------------------------------------------------------
// f32 -> bf16 conversion for x + all 8 weights, one launch.
// ---------------------------------------------------------------------------
__global__ __launch_bounds__(256)
void cvt_all(const float* __restrict__ x,  const float* __restrict__ w0,
             const float* __restrict__ w1, const float* __restrict__ w2,
             const float* __restrict__ w3, const float* __restrict__ w4,
             const float* __restrict__ w5, const float* __restrict__ w6,
             const float* __restrict__ w7,
             short* xb, short* o0, short* o1, short* o2, short* o3,
             short* o4, short* o5, short* o6, short* o7)
{
    int bid = blockIdx.x;
    const float* src; short* dst; int rel;
    if      (bid < 4096) { src = x;  dst = xb; rel = bid; }
    else if (bid < 4608) { src = w0; dst = o0; rel = bid - 4096; }
    else if (bid < 4992) { src = w1; dst = o1; rel = bid - 4608; }
    else if (bid < 5120) { src = w2; dst = o2; rel = bid - 4992; }
    else if (bid < 5632) { src = w3; dst = o3; rel = bid - 5120; }
    else if (bid < 6016) { src = w4; dst = o4; rel = bid - 5632; }
    else if (bid < 6048) { src = w5; dst = o5; rel = bid - 6016; }
    else if (bid < 6560) { src = w6; dst = o6; rel = bid - 6048; }
    else                 { src = w7; dst = o7; rel = bid - 6560; }
    int base = rel * 2048 + threadIdx.x * 8;
    float4 a = *(const float4*)(src + base);
    float4 b = *(const float4*)(src + base + 4);
    s4_t r0 = { f2bf(a.x), f2bf(a.y), f2bf(a.z), f2bf(a.w) };
    s4_t r1 = { f2bf(b.x), f2bf(b.y), f2bf(b.z), f2bf(b.w) };
    *(s4_t*)(dst + base)     = r0;
    *(s4_t*)(dst + base + 4) = r1;
}

// ---------------------------------------------------------------------------
// bf16 MFMA NT GEMM, double-buffered (one barrier per k-step).
// 128x128 tile, BK=32, 4 waves, 4x4 16x16x32 frags, swizzled gload16 staging.
// EPI_DOWN: W = [Wq_down|Wkv_down|Wk_rope] (1056 rows, K=2048).
//           n<1024 -> qkvlat (ldc 1024); 1024<=n<1056 -> krt (ldc 32).
// EPI_UP:   two jobs in one dispatch (K=512, lda 1024):
//           by<16: A=qkvlat[:, :512], W=wqur, N=2048:
//                  n<1536 -> head-major qh; else qrt[m][n-1536]
//           by>=16: A=qkvlat[:,512:], W=wkvu, N=3584:
//                  n<1536 -> head-major kh; else vT[b][h][d][s]
// EPI_WO:   f32 + bias -> out (ldc 2048, K=2048).
// ---------------------------------------------------------------------------
#define EPI_DOWN 0
#define EPI_UP   1
#define EPI_WO   2

template<int KTOT, int EPI>
__global__ __launch_bounds__(256)
void gemm_t(const short* __restrict__ A, const short* __restrict__ W,
            const short* __restrict__ W2,
            void* __restrict__ o1, void* __restrict__ o2,
            void* __restrict__ o3, void* __restrict__ o4,
            const float* __restrict__ bias)
{
    __shared__ short As[2][4096];
    __shared__ short Bs[2][4096];
    const int tid  = threadIdx.x;
    const int w    = tid >> 6;
    const int lane = tid & 63;
    const int l16  = lane & 15;
    const int quad = lane >> 4;
    const int m0 = blockIdx.x * 128;
    int n0 = blockIdx.y * 128;
    const int wm = (w & 1) * 64;
    const int wn = (w >> 1) * 64;

    const short* Ap = A;
    const short* Wp = W;
    int lda, Nrow, job = 0;
    if (EPI == EPI_DOWN) { lda = 2048; Nrow = 1056; }
    if (EPI == EPI_WO)   { lda = 2048; Nrow = 2048; }
    if (EPI == EPI_UP) {
        lda = 1024;
        if (blockIdx.y < 16) { Nrow = 2048; }
        else { job = 1; Ap = A + 512; Wp = W2; n0 = ((int)blockIdx.y - 16) * 128; Nrow = 3584; }
    }

    int srow[2], skc[2], ldso[2];
#pragma unroll
    for (int j = 0; j < 2; ++j) {
        int c = (w * 32 + j * 16) * 4 + lane;
        srow[j] = c >> 2;
        skc[j]  = (c & 3) ^ (srow[j] & 3);
        ldso[j] = (w * 32 + j * 16) * 32;
    }
    const int xq = quad ^ (l16 & 3);

    auto stage = [&](int k0, int buf) {
#pragma unroll
        for (int j = 0; j < 2; ++j) {
            const short* ga = Ap + (size_t)(m0 + srow[j]) * lda + k0 + skc[j] * 8;
            gload16(ga, &As[buf][ldso[j]]);
            int gn = n0 + srow[j]; if (gn >= Nrow) gn = Nrow - 1;
            const short* gb = Wp + (size_t)gn * KTOT + k0 + skc[j] * 8;
            gload16(gb, &Bs[buf][ldso[j]]);
        }
    };

    f4_t acc[4][4];
#pragma unroll
    for (int i = 0; i < 4; ++i)
#pragma unroll
        for (int j = 0; j < 4; ++j) acc[i][j] = (f4_t){0.f, 0.f, 0.f, 0.f};

    stage(0, 0);
    const int nk = KTOT / 32;
    for (int t = 0; t < nk; ++t) {
        const int cur = t & 1;
        __syncthreads();           // drains prev staging; buf[cur] ready
        if (t + 1 < nk) stage((t + 1) * 32, cur ^ 1);
        bf8_t af[4], bfr[4];
#pragma unroll
        for (int i = 0; i < 4; ++i)
            af[i] = *(const bf8_t*)&As[cur][((wm + i * 16 + l16) * 4 + xq) * 8];
#pragma unroll
        for (int j = 0; j < 4; ++j)
            bfr[j] = *(const bf8_t*)&Bs[cur][((wn + j * 16 + l16) * 4 + xq) * 8];
#pragma unroll
        for (int i = 0; i < 4; ++i)
#pragma unroll
            for (int j = 0; j < 4; ++j)
                acc[i][j] = __builtin_amdgcn_mfma_f32_16x16x32_bf16(
                    af[i], bfr[j], acc[i][j], 0, 0, 0);
    }

    // epilogue (C layout: col = l16, row = quad*4 + r)
#pragma unroll
    for (int mi = 0; mi < 4; ++mi) {
#pragma unroll
        for (int nj = 0; nj < 4; ++nj) {
            const int gm = m0 + wm + mi * 16 + quad * 4;
            const int gn = n0 + wn + nj * 16 + l16;
            const int bb = gm >> 11, ss = gm & 2047;
            if (EPI == EPI_DOWN) {
                if (n0 < 1024) {
                    short* o = (short*)o1 + (size_t)gm * 1024 + gn;
#pragma unroll
                    for (int r = 0; r < 4; ++r) o[(size_t)r * 1024] = f2bf(acc[mi][nj][r]);
                } else if (gn < 1056) {
                    short* o = (short*)o2 + (size_t)gm * 32 + (gn - 1024);
#pragma unroll
                    for (int r = 0; r < 4; ++r) o[(size_t)r * 32] = f2bf(acc[mi][nj][r]);
                }
            } else if (EPI == EPI_WO) {
                float* o = (float*)o1 + (size_t)gm * 2048 + gn;
                float bv = bias[gn];
#pragma unroll
                for (int r = 0; r < 4; ++r) o[(size_t)r * 2048] = acc[mi][nj][r] + bv;
            } else { // EPI_UP
                if (job == 0) {
                    if (gn < 1536) {
                        int hh = gn / CDIM, cc = gn % CDIM;
                        short* o = (short*)o1 +
                            (((size_t)(bb * NH + hh) * SEQ + ss) * DHD + cc);
#pragma unroll
                        for (int r = 0; r < 4; ++r) o[(size_t)r * DHD] = f2bf(acc[mi][nj][r]);
                    } else {
                        short* o = (short*)o2 + (size_t)gm * 512 + (gn - 1536);
#pragma unroll
                        for (int r = 0; r < 4; ++r) o[(size_t)r * 512] = f2bf(acc[mi][nj][r]);
                    }
                } else {
                    if (gn < 1536) {
                        int hh = gn / CDIM, cc = gn % CDIM;
                        short* o = (short*)o3 +
                            (((size_t)(bb * NH + hh) * SEQ + ss) * DHD + cc);
#pragma unroll
                        for (int r = 0; r < 4; ++r) o[(size_t)r * DHD] = f2bf(acc[mi][nj][r]);
                    } else {
                        int n2 = gn - 1536;
                        int h2 = n2 >> 7, dh = n2 & 127;
                        size_t idx = ((size_t)(bb * NH + h2) * DHD + dh) * SEQ + ss;
                        s4_t pk = { f2bf(acc[mi][nj][0]), f2bf(acc[mi][nj][1]),
                                    f2bf(acc[mi][nj][2]), f2bf(acc[mi][nj][3]) };
                        *(s4_t*)((short*)o4 + idx) = pk;
                    }
                }
            }
        }
    }
}

// ---------------------------------------------------------------------------
// RoPE (bf16), head-major outputs [b][h][s][128]
// ---------------------------------------------------------------------------
__global__ void rope_q_kernel(const short* __restrict__ qr, short* __restrict__ qh)
{
    int idx = blockIdx.x * blockDim.x + threadIdx.x;
    int m = idx >> 9;
    int h = (idx >> 5) & 15;
    int r = idx & 31;
    int b = m >> 11, s = m & (SEQ - 1);
    float invf = expf(-((float)(2 * (r & 15)) / 32.0f) * 9.210340371976184f);
    float f = (float)s * invf;
    float cs = cosf(f), sn = sinf(f);
    float val = bf2f(qr[(size_t)m * 512 + h * 32 + r]);
    float partner = bf2f(qr[(size_t)m * 512 + h * 32 + (r ^ 16)]);
    float rot = (r < 16) ? -partner : partner;
    qh[((size_t)(b * NH + h) * SEQ + s) * DHD + CDIM + r] = f2bf(val * cs + rot * sn);
}

__global__ void rope_k_kernel(const short* __restrict__ kr, short* __restrict__ kh)
{
    int idx = blockIdx.x * blockDim.x + threadIdx.x;
    int m = idx >> 5;
    int r = idx & 31;
    int b = m >> 11, s = m & (SEQ - 1);
    float invf = expf(-((float)(2 * (r & 15)) / 32.0f) * 9.210340371976184f);
    float f = (float)s * invf;
    float cs = cosf(f), sn = sinf(f);
    float val = bf2f(kr[(size_t)m * 32 + r]);
    float partner = bf2f(kr[(size_t)m * 32 + (r ^ 16)]);
    float rot = (r < 16) ? -partner : partner;
    short o = f2bf(val * cs + rot * sn);
    short* dst = kh + ((size_t)b * NH * SEQ + s) * DHD + CDIM + r;
#pragma unroll
    for (int h = 0; h < NH; ++h) dst[(size_t)h * SEQ * DHD] = o;
}

// ---------------------------------------------------------------------------
// MFMA flash attention v3: causal load-balanced pairing (qb, 31-qb),
// 68 key-tiles per block. BQ=64 (16 rows/wave), BK=32, double-buffered
// gload16 prefetch, swizzled LDS (<=2-way conflicts), Q pre-scaled.
// ---------------------------------------------------------------------------
__global__ __launch_bounds__(256)
void attn_mfma(const short* __restrict__ qh, const short* __restrict__ kh,
               const short* __restrict__ vt, short* __restrict__ ctx)
{
    const int h = blockIdx.y, b = blockIdx.z;
    __shared__ short Ks[2][4096];
    __shared__ short Vs[2][4096];
    __shared__ short Ps[4][16][40];
    const int tid  = threadIdx.x;
    const int w    = tid >> 6;
    const int lane = tid & 63;
    const int l16  = lane & 15;
    const int quad = lane >> 4;
    const float scale = 0.08838834764831845f;  // 1/sqrt(128)

    const short* khead = kh + (size_t)(b * NH + h) * SEQ * DHD;
    const short* vhead = vt + (size_t)(b * NH + h) * DHD * SEQ;

    int koff[2], voff[2], ldso[2];
#pragma unroll
    for (int j = 0; j < 2; ++j) {
        int s = j * 256 + tid;
        int key = s >> 4, dch = (s & 15) ^ (key & 15);
        koff[j] = key * DHD + dch * 8;
        int d = s >> 2, kc = (s & 3) ^ ((d >> 1) & 3);
        voff[j] = d * SEQ + kc * 8;
        ldso[j] = (j * 256 + w * 64) * 8;
    }

    for (int phase = 0; phase < 2; ++phase) {
        const int qb = phase ? (31 - (int)blockIdx.x) : (int)blockIdx.x;
        const int q0 = qb * 64;

        bf8_t qf[4];
        {
            const short* qp = qh + ((size_t)(b * NH + h) * SEQ + q0 + w * 16 + l16) * DHD
                                 + quad * 8;
#pragma unroll
            for (int ks = 0; ks < 4; ++ks) {
                bf8_t raw = *(const bf8_t*)(qp + ks * 32);
#pragma unroll
                for (int j = 0; j < 8; ++j) qf[ks][j] = f2bf(bf2f(raw[j]) * scale);
            }
        }

        f4_t O[8];
#pragma unroll
        for (int i = 0; i < 8; ++i) O[i] = (f4_t){0.f, 0.f, 0.f, 0.f};
        float m_run[4], l_run[4];
#pragma unroll
        for (int r = 0; r < 4; ++r) { m_run[r] = -3e38f; l_run[r] = 0.f; }

        const int ntiles = 2 * qb + 2;
        __syncthreads();   // previous phase's LDS reads done
#pragma unroll
        for (int j = 0; j < 2; ++j) {
            gload16(khead + koff[j], &Ks[0][ldso[j]]);
            gload16(vhead + voff[j], &Vs[0][ldso[j]]);
        }

        for (int t = 0; t < ntiles; ++t) {
            const int cur = t & 1;
            const int c0 = t * 32;
            __syncthreads();
            if (t + 1 < ntiles) {
                const short* kt = khead + (size_t)(c0 + 32) * DHD;
#pragma unroll
                for (int j = 0; j < 2; ++j) {
                    gload16(kt + koff[j], &Ks[cur ^ 1][ldso[j]]);
                    gload16(vhead + voff[j] + c0 + 32, &Vs[cur ^ 1][ldso[j]]);
                }
            }

            f4_t S0 = {0.f, 0.f, 0.f, 0.f}, S1 = {0.f, 0.f, 0.f, 0.f};
#pragma unroll
            for (int ks = 0; ks < 4; ++ks) {
                int dch = ks * 4 + quad;
                int si0 = l16 * 16 + (dch ^ l16);
                int si1 = (l16 + 16) * 16 + (dch ^ l16);
                bf8_t b0 = *(const bf8_t*)&Ks[cur][si0 * 8];
                bf8_t b1 = *(const bf8_t*)&Ks[cur][si1 * 8];
                S0 = __builtin_amdgcn_mfma_f32_16x16x32_bf16(qf[ks], b0, S0, 0, 0, 0);
                S1 = __builtin_amdgcn_mfma_f32_16x16x32_bf16(qf[ks], b1, S1, 0, 0, 0);
            }

            const int grow0 = q0 + w * 16 + quad * 4;
            float alpha[4];
#pragma unroll
            for (int r = 0; r < 4; ++r) {
                const int grow = grow0 + r;
                float s0 = (c0 + l16      <= grow) ? S0[r] : -3e38f;
                float s1 = (c0 + l16 + 16 <= grow) ? S1[r] : -3e38f;
                float mx = fmaxf(s0, s1);
                mx = fmaxf(mx, __shfl_xor(mx, 1));
                mx = fmaxf(mx, __shfl_xor(mx, 2));
                mx = fmaxf(mx, __shfl_xor(mx, 4));
                mx = fmaxf(mx, __shfl_xor(mx, 8));
                const float mnew = fmaxf(m_run[r], mx);
                alpha[r] = __expf(m_run[r] - mnew);
                const float p0 = __expf(s0 - mnew);
                const float p1 = __expf(s1 - mnew);
                float rs = p0 + p1;
                rs += __shfl_xor(rs, 1);
                rs += __shfl_xor(rs, 2);
                rs += __shfl_xor(rs, 4);
                rs += __shfl_xor(rs, 8);
                l_run[r] = alpha[r] * l_run[r] + rs;
                m_run[r] = mnew;
                Ps[w][quad * 4 + r][l16]      = f2bf(p0);
                Ps[w][quad * 4 + r][l16 + 16] = f2bf(p1);
            }

#pragma unroll
            for (int dt = 0; dt < 8; ++dt)
#pragma unroll
                for (int r = 0; r < 4; ++r) O[dt][r] *= alpha[r];

            bf8_t pf = *(const bf8_t*)&Ps[w][l16][quad * 8];
#pragma unroll
            for (int dt = 0; dt < 8; ++dt) {
                int d = dt * 16 + l16;
                int si = d * 4 + (quad ^ ((d >> 1) & 3));
                bf8_t vf = *(const bf8_t*)&Vs[cur][si * 8];
                O[dt] = __builtin_amdgcn_mfma_f32_16x16x32_bf16(pf, vf, O[dt], 0, 0, 0);
            }
        }

        float inv_l[4];
#pragma unroll
        for (int r = 0; r < 4; ++r) inv_l[r] = 1.0f / l_run[r];
        short* cbase = ctx + (size_t)(b * SEQ + q0 + w * 16 + quad * 4) * HIDN
                           + h * DHD + l16;
#pragma unroll
        for (int r = 0; r < 4; ++r)
#pragma unroll
            for (int dt = 0; dt < 8; ++dt)
                cbase[(size_t)r * HIDN + dt * 16] = f2bf(O[dt][r] * inv_l[r]);
    }
}

// ---------------------------------------------------------------------------
extern "C" void kernel_launch(void* const* d_in, const int* in_sizes, int n_in,
                              void* d_out, int out_size, void* d_ws, size_t ws_size,
                              hipStream_t stream)
{
    const float* x        = (const float*)d_in[0];
    const float* Wq_down  = (const float*)d_in[1];
    const float* Wq_up    = (const float*)d_in[2];
    const float* Wq_rope  = (const float*)d_in[3];
    const float* Wkv_down = (const float*)d_in[4];
    const float* Wk_up    = (const float*)d_in[5];
    const float* Wk_rope  = (const float*)d_in[6];
    const float* Wv_up    = (const float*)d_in[7];
    const float* Wo       = (const float*)d_in[8];
    const float* bo       = (const float*)d_in[9];
    float* out = (float*)d_out;

    // workspace (bf16 shorts)
    short* ws     = (short*)d_ws;
    short* xb     = ws;                 //  8388608
    short* wdownc = ws + 8388608;       //  2162688  [Wq_down|Wkv_down|Wk_rope] 1056 rows
    short* wqur   = ws + 10551296;      //  1048576  [Wq_up | Wq_rope]
    short* wkvu   = ws + 11599872;      //  1835008  [Wk_up | Wv_up]
    short* wob    = ws + 13434880;      //  4194304
    short* qkvlat = ws + 17629184;      //  4194304  [4096][1024] = qlat|kvlat
    short* qhb    = ws + 21823488;      //  8388608  [b][h][s][128]
    short* khb    = ws + 30212096;      //  8388608  [b][h][s][128]
    short* vtw    = ws + 38600704;      //  8388608  [b][h][d][s]
    short* ctxb   = ws + 46989312;      //  8388608  [b][s][2048]
    short* qrt    = ws + 55377920;      //  2097152
    short* krt    = ws + 57475072;      //   131072

    dim3 blk(256);
    cvt_all<<<dim3(8608), blk, 0, stream>>>(
        x, Wq_down, Wq_up, Wq_rope, Wkv_down, Wk_up, Wk_rope, Wv_up, Wo,
        xb, wdownc, wqur, wqur + 786432, wdownc + 1048576,
        wkvu, wdownc + 2097152, wkvu + 786432, wob);

    // down-combo + k-rope: [q_lat | kv_lat] and krt
    gemm_t<2048, EPI_DOWN><<<dim3(32, 9), blk, 0, stream>>>(
        xb, wdownc, nullptr, qkvlat, krt, nullptr, nullptr, nullptr);
    // merged up-stage: q-combo (by<16) + kv-combo (by>=16)
    gemm_t<512, EPI_UP><<<dim3(32, 44), blk, 0, stream>>>(
        qkvlat, wqur, wkvu, qhb, qrt, khb, vtw, nullptr);

    rope_q_kernel<<<dim3(MTOT * NH * RD / 256), blk, 0, stream>>>(qrt, qhb);
    rope_k_kernel<<<dim3(MTOT * RD / 256), blk, 0, stream>>>(krt, khb);

    attn_mfma<<<dim3(16, NH, NB), blk, 0, stream>>>(qhb, khb, vtw, ctxb);

    gemm_t<2048, EPI_WO><<<dim3(32, 16), blk, 0, stream>>>(
        ctxb, wob, nullptr, out, nullptr, nullptr, nullptr, bo);
}

// Round 7
// 355.244 us; speedup vs baseline: 10.3518x; 1.1352x over previous
//
#include <hip/hip_runtime.h>
#include <math.h>

// Problem constants
#define HIDN 2048
#define NH   16
#define LATN 512
#define RD   32
#define DHD  128
#define CDIM 96
#define NB   2
#define SEQ  2048
#define MTOT 4096   // NB*SEQ token rows

typedef __attribute__((ext_vector_type(8))) short bf8_t;   // 8 x bf16 (4 VGPRs)
typedef __attribute__((ext_vector_type(4))) float f4_t;    // MFMA C/D frag
typedef __attribute__((ext_vector_type(4))) short s4_t;    // 4 x bf16 (8 B)

__device__ __forceinline__ short f2bf(float f) {
    union { float f; unsigned u; } x; x.f = f;
    unsigned r = x.u + 0x7fffu + ((x.u >> 16) & 1u);   // round-to-nearest-even
    return (short)(r >> 16);
}
__device__ __forceinline__ float bf2f(short s) {
    union { float f; unsigned u; } x; x.u = ((unsigned)(unsigned short)s) << 16;
    return x.f;
}
// async global->LDS, 16B per lane, lane i lands at ldsbase + i*16
__device__ __forceinline__ void gload16(const void* g, void* l) {
    __builtin_amdgcn_global_load_lds(
        (const __attribute__((address_space(1))) void*)g,
        (__attribute__((address_space(3))) void*)l, 16, 0, 0);
}

// 16-lane all-reduce via DPP (VALU-only): xor1, xor2 quad_perms + row_ror 4,8
__device__ __forceinline__ float dpp_max16(float x) {
    union { float f; int i; } a, t; a.f = x;
    t.i = __builtin_amdgcn_update_dpp(0, a.i, 0xB1,  0xF, 0xF, true); a.f = fmaxf(a.f, t.f);
    t.i = __builtin_amdgcn_update_dpp(0, a.i, 0x4E,  0xF, 0xF, true); a.f = fmaxf(a.f, t.f);
    t.i = __builtin_amdgcn_update_dpp(0, a.i, 0x124, 0xF, 0xF, true); a.f = fmaxf(a.f, t.f);
    t.i = __builtin_amdgcn_update_dpp(0, a.i, 0x128, 0xF, 0xF, true); a.f = fmaxf(a.f, t.f);
    return a.f;
}
__device__ __forceinline__ float dpp_sum16(float x) {
    union { float f; int i; } a, t; a.f = x;
    t.i = __builtin_amdgcn_update_dpp(0, a.i, 0xB1,  0xF, 0xF, true); a.f += t.f;
    t.i = __builtin_amdgcn_update_dpp(0, a.i, 0x4E,  0xF, 0xF, true); a.f += t.f;
    t.i = __builtin_amdgcn_update_dpp(0, a.i, 0x124, 0xF, 0xF, true); a.f += t.f;
    t.i = __builtin_amdgcn_update_dpp(0, a.i, 0x128, 0xF, 0xF, true); a.f += t.f;
    return a.f;
}

// ---------------------------------------------------------------------------
// f32 -> bf16 conversion for x + all 8 weights, one launch.
// ---------------------------------------------------------------------------
__global__ __launch_bounds__(256)
void cvt_all(const float* __restrict__ x,  const float* __restrict__ w0,
             const float* __restrict__ w1, const float* __restrict__ w2,
             const float* __restrict__ w3, const float* __restrict__ w4,
             const float* __restrict__ w5, const float* __restrict__ w6,
             const float* __restrict__ w7,
             short* xb, short* o0, short* o1, short* o2, short* o3,
             short* o4, short* o5, short* o6, short* o7)
{
    int bid = blockIdx.x;
    const float* src; short* dst; int rel;
    if      (bid < 4096) { src = x;  dst = xb; rel = bid; }
    else if (bid < 4608) { src = w0; dst = o0; rel = bid - 4096; }
    else if (bid < 4992) { src = w1; dst = o1; rel = bid - 4608; }
    else if (bid < 5120) { src = w2; dst = o2; rel = bid - 4992; }
    else if (bid < 5632) { src = w3; dst = o3; rel = bid - 5120; }
    else if (bid < 6016) { src = w4; dst = o4; rel = bid - 5632; }
    else if (bid < 6048) { src = w5; dst = o5; rel = bid - 6016; }
    else if (bid < 6560) { src = w6; dst = o6; rel = bid - 6048; }
    else                 { src = w7; dst = o7; rel = bid - 6560; }
    int base = rel * 2048 + threadIdx.x * 8;
    float4 a = *(const float4*)(src + base);
    float4 b = *(const float4*)(src + base + 4);
    s4_t r0 = { f2bf(a.x), f2bf(a.y), f2bf(a.z), f2bf(a.w) };
    s4_t r1 = { f2bf(b.x), f2bf(b.y), f2bf(b.z), f2bf(b.w) };
    *(s4_t*)(dst + base)     = r0;
    *(s4_t*)(dst + base + 4) = r1;
}

// ---------------------------------------------------------------------------
// bf16 MFMA NT GEMM, double-buffered (one barrier per k-step). Unchanged R6.
// ---------------------------------------------------------------------------
#define EPI_DOWN 0
#define EPI_UP   1
#define EPI_WO   2

template<int KTOT, int EPI>
__global__ __launch_bounds__(256)
void gemm_t(const short* __restrict__ A, const short* __restrict__ W,
            const short* __restrict__ W2,
            void* __restrict__ o1, void* __restrict__ o2,
            void* __restrict__ o3, void* __restrict__ o4,
            const float* __restrict__ bias)
{
    __shared__ short As[2][4096];
    __shared__ short Bs[2][4096];
    const int tid  = threadIdx.x;
    const int w    = tid >> 6;
    const int lane = tid & 63;
    const int l16  = lane & 15;
    const int quad = lane >> 4;
    const int m0 = blockIdx.x * 128;
    int n0 = blockIdx.y * 128;
    const int wm = (w & 1) * 64;
    const int wn = (w >> 1) * 64;

    const short* Ap = A;
    const short* Wp = W;
    int lda, Nrow, job = 0;
    if (EPI == EPI_DOWN) { lda = 2048; Nrow = 1056; }
    if (EPI == EPI_WO)   { lda = 2048; Nrow = 2048; }
    if (EPI == EPI_UP) {
        lda = 1024;
        if (blockIdx.y < 16) { Nrow = 2048; }
        else { job = 1; Ap = A + 512; Wp = W2; n0 = ((int)blockIdx.y - 16) * 128; Nrow = 3584; }
    }

    int srow[2], skc[2], ldso[2];
#pragma unroll
    for (int j = 0; j < 2; ++j) {
        int c = (w * 32 + j * 16) * 4 + lane;
        srow[j] = c >> 2;
        skc[j]  = (c & 3) ^ (srow[j] & 3);
        ldso[j] = (w * 32 + j * 16) * 32;
    }
    const int xq = quad ^ (l16 & 3);

    auto stage = [&](int k0, int buf) {
#pragma unroll
        for (int j = 0; j < 2; ++j) {
            const short* ga = Ap + (size_t)(m0 + srow[j]) * lda + k0 + skc[j] * 8;
            gload16(ga, &As[buf][ldso[j]]);
            int gn = n0 + srow[j]; if (gn >= Nrow) gn = Nrow - 1;
            const short* gb = Wp + (size_t)gn * KTOT + k0 + skc[j] * 8;
            gload16(gb, &Bs[buf][ldso[j]]);
        }
    };

    f4_t acc[4][4];
#pragma unroll
    for (int i = 0; i < 4; ++i)
#pragma unroll
        for (int j = 0; j < 4; ++j) acc[i][j] = (f4_t){0.f, 0.f, 0.f, 0.f};

    stage(0, 0);
    const int nk = KTOT / 32;
    for (int t = 0; t < nk; ++t) {
        const int cur = t & 1;
        __syncthreads();
        if (t + 1 < nk) stage((t + 1) * 32, cur ^ 1);
        bf8_t af[4], bfr[4];
#pragma unroll
        for (int i = 0; i < 4; ++i)
            af[i] = *(const bf8_t*)&As[cur][((wm + i * 16 + l16) * 4 + xq) * 8];
#pragma unroll
        for (int j = 0; j < 4; ++j)
            bfr[j] = *(const bf8_t*)&Bs[cur][((wn + j * 16 + l16) * 4 + xq) * 8];
#pragma unroll
        for (int i = 0; i < 4; ++i)
#pragma unroll
            for (int j = 0; j < 4; ++j)
                acc[i][j] = __builtin_amdgcn_mfma_f32_16x16x32_bf16(
                    af[i], bfr[j], acc[i][j], 0, 0, 0);
    }

#pragma unroll
    for (int mi = 0; mi < 4; ++mi) {
#pragma unroll
        for (int nj = 0; nj < 4; ++nj) {
            const int gm = m0 + wm + mi * 16 + quad * 4;
            const int gn = n0 + wn + nj * 16 + l16;
            const int bb = gm >> 11, ss = gm & 2047;
            if (EPI == EPI_DOWN) {
                if (n0 < 1024) {
                    short* o = (short*)o1 + (size_t)gm * 1024 + gn;
#pragma unroll
                    for (int r = 0; r < 4; ++r) o[(size_t)r * 1024] = f2bf(acc[mi][nj][r]);
                } else if (gn < 1056) {
                    short* o = (short*)o2 + (size_t)gm * 32 + (gn - 1024);
#pragma unroll
                    for (int r = 0; r < 4; ++r) o[(size_t)r * 32] = f2bf(acc[mi][nj][r]);
                }
            } else if (EPI == EPI_WO) {
                float* o = (float*)o1 + (size_t)gm * 2048 + gn;
                float bv = bias[gn];
#pragma unroll
                for (int r = 0; r < 4; ++r) o[(size_t)r * 2048] = acc[mi][nj][r] + bv;
            } else { // EPI_UP
                if (job == 0) {
                    if (gn < 1536) {
                        int hh = gn / CDIM, cc = gn % CDIM;
                        short* o = (short*)o1 +
                            (((size_t)(bb * NH + hh) * SEQ + ss) * DHD + cc);
#pragma unroll
                        for (int r = 0; r < 4; ++r) o[(size_t)r * DHD] = f2bf(acc[mi][nj][r]);
                    } else {
                        short* o = (short*)o2 + (size_t)gm * 512 + (gn - 1536);
#pragma unroll
                        for (int r = 0; r < 4; ++r) o[(size_t)r * 512] = f2bf(acc[mi][nj][r]);
                    }
                } else {
                    if (gn < 1536) {
                        int hh = gn / CDIM, cc = gn % CDIM;
                        short* o = (short*)o3 +
                            (((size_t)(bb * NH + hh) * SEQ + ss) * DHD + cc);
#pragma unroll
                        for (int r = 0; r < 4; ++r) o[(size_t)r * DHD] = f2bf(acc[mi][nj][r]);
                    } else {
                        int n2 = gn - 1536;
                        int h2 = n2 >> 7, dh = n2 & 127;
                        size_t idx = ((size_t)(bb * NH + h2) * DHD + dh) * SEQ + ss;
                        s4_t pk = { f2bf(acc[mi][nj][0]), f2bf(acc[mi][nj][1]),
                                    f2bf(acc[mi][nj][2]), f2bf(acc[mi][nj][3]) };
                        *(s4_t*)((short*)o4 + idx) = pk;
                    }
                }
            }
        }
    }
}

// ---------------------------------------------------------------------------
// RoPE (bf16), head-major outputs [b][h][s][128]
// ---------------------------------------------------------------------------
__global__ void rope_q_kernel(const short* __restrict__ qr, short* __restrict__ qh)
{
    int idx = blockIdx.x * blockDim.x + threadIdx.x;
    int m = idx >> 9;
    int h = (idx >> 5) & 15;
    int r = idx & 31;
    int b = m >> 11, s = m & (SEQ - 1);
    float invf = expf(-((float)(2 * (r & 15)) / 32.0f) * 9.210340371976184f);
    float f = (float)s * invf;
    float cs = cosf(f), sn = sinf(f);
    float val = bf2f(qr[(size_t)m * 512 + h * 32 + r]);
    float partner = bf2f(qr[(size_t)m * 512 + h * 32 + (r ^ 16)]);
    float rot = (r < 16) ? -partner : partner;
    qh[((size_t)(b * NH + h) * SEQ + s) * DHD + CDIM + r] = f2bf(val * cs + rot * sn);
}

__global__ void rope_k_kernel(const short* __restrict__ kr, short* __restrict__ kh)
{
    int idx = blockIdx.x * blockDim.x + threadIdx.x;
    int m = idx >> 5;
    int r = idx & 31;
    int b = m >> 11, s = m & (SEQ - 1);
    float invf = expf(-((float)(2 * (r & 15)) / 32.0f) * 9.210340371976184f);
    float f = (float)s * invf;
    float cs = cosf(f), sn = sinf(f);
    float val = bf2f(kr[(size_t)m * 32 + r]);
    float partner = bf2f(kr[(size_t)m * 32 + (r ^ 16)]);
    float rot = (r < 16) ? -partner : partner;
    short o = f2bf(val * cs + rot * sn);
    short* dst = kh + ((size_t)b * NH * SEQ + s) * DHD + CDIM + r;
#pragma unroll
    for (int h = 0; h < NH; ++h) dst[(size_t)h * SEQ * DHD] = o;
}

// ---------------------------------------------------------------------------
// MFMA flash attention v4: BK=64, DPP softmax, exp2 domain.
// Causal pairing (qb, 31-qb): ntiles = (qb+1) + (32-qb) = 33 per block.
// BQ=64 (16 q-rows/wave). K tile [64 keys][128 d], V tile [128 d][64 keys]
// (pre-transposed), both via swizzled gload16 (uniform-bank b128 reads).
// Double-buffered, 1 barrier/tile. Q pre-scaled by log2(e)/sqrt(D).
// LDS: Ks 2x16K + Vs 2x16K + Ps 9.2K = 73.2 KB -> 2 blocks/CU.
// ---------------------------------------------------------------------------
__global__ __launch_bounds__(256)
void attn_mfma(const short* __restrict__ qh, const short* __restrict__ kh,
               const short* __restrict__ vt, short* __restrict__ ctx)
{
    const int h = blockIdx.y, b = blockIdx.z;
    __shared__ short Ks[2][8192];   // 64 keys x 128 d
    __shared__ short Vs[2][8192];   // 128 d x 64 keys
    __shared__ short Ps[4][16][72];
    const int tid  = threadIdx.x;
    const int w    = tid >> 6;
    const int lane = tid & 63;
    const int l16  = lane & 15;
    const int quad = lane >> 4;
    const float qscale = 0.12752956f;   // (1/sqrt(128)) * log2(e)

    const short* khead = kh + (size_t)(b * NH + h) * SEQ * DHD;
    const short* vhead = vt + (size_t)(b * NH + h) * DHD * SEQ;

    // staging decode: 4 slots/thread for K and V (1024 slots each)
    int koff[4], voff[4], ldso[4];
#pragma unroll
    for (int j = 0; j < 4; ++j) {
        int s = j * 256 + tid;
        int key = s >> 4, c = s & 15;
        koff[j] = key * DHD + (c ^ (key & 15)) * 8;
        int d = s >> 3, c2 = s & 7;
        voff[j] = d * SEQ + (c2 ^ (d & 7)) * 8;
        ldso[j] = (j * 256 + w * 64) * 8;
    }

    for (int phase = 0; phase < 2; ++phase) {
        const int qb = phase ? (31 - (int)blockIdx.x) : (int)blockIdx.x;
        const int q0 = qb * 64;

        // Q A-frags, pre-scaled into exp2 domain
        bf8_t qf[4];
        {
            const short* qp = qh + ((size_t)(b * NH + h) * SEQ + q0 + w * 16 + l16) * DHD
                                 + quad * 8;
#pragma unroll
            for (int ks = 0; ks < 4; ++ks) {
                bf8_t raw = *(const bf8_t*)(qp + ks * 32);
#pragma unroll
                for (int j = 0; j < 8; ++j) qf[ks][j] = f2bf(bf2f(raw[j]) * qscale);
            }
        }

        f4_t O[8];
#pragma unroll
        for (int i = 0; i < 8; ++i) O[i] = (f4_t){0.f, 0.f, 0.f, 0.f};
        float m_run[4], l_run[4];
#pragma unroll
        for (int r = 0; r < 4; ++r) { m_run[r] = -3e38f; l_run[r] = 0.f; }

        const int ntiles = qb + 1;
        __syncthreads();   // previous phase's LDS reads done
#pragma unroll
        for (int j = 0; j < 4; ++j) {
            gload16(khead + koff[j], &Ks[0][ldso[j]]);
            gload16(vhead + voff[j], &Vs[0][ldso[j]]);
        }

        for (int t = 0; t < ntiles; ++t) {
            const int cur = t & 1;
            const int c0 = t * 64;
            __syncthreads();
            if (t + 1 < ntiles) {
                const short* kt = khead + (size_t)(c0 + 64) * DHD;
#pragma unroll
                for (int j = 0; j < 4; ++j) {
                    gload16(kt + koff[j], &Ks[cur ^ 1][ldso[j]]);
                    gload16(vhead + voff[j] + c0 + 64, &Vs[cur ^ 1][ldso[j]]);
                }
            }

            // S = Q K^T : 16 q-rows x 64 keys (4 sub-tiles x 4 k-steps)
            f4_t S[4];
#pragma unroll
            for (int j = 0; j < 4; ++j) S[j] = (f4_t){0.f, 0.f, 0.f, 0.f};
#pragma unroll
            for (int ks = 0; ks < 4; ++ks) {
                const int dch = ks * 4 + quad;
#pragma unroll
                for (int j = 0; j < 4; ++j) {
                    const int slot = (j * 16 + l16) * 16 + (dch ^ l16);
                    bf8_t bj = *(const bf8_t*)&Ks[cur][slot * 8];
                    S[j] = __builtin_amdgcn_mfma_f32_16x16x32_bf16(qf[ks], bj, S[j], 0, 0, 0);
                }
            }

            // causal mask + online softmax, exp2 domain, DPP reductions
            const int grow0 = q0 + w * 16 + quad * 4;
            float alpha[4];
#pragma unroll
            for (int r = 0; r < 4; ++r) {
                const int grow = grow0 + r;
                float sv[4];
#pragma unroll
                for (int j = 0; j < 4; ++j)
                    sv[j] = (c0 + j * 16 + l16 <= grow) ? S[j][r] : -3e38f;
                float mx = fmaxf(fmaxf(sv[0], sv[1]), fmaxf(sv[2], sv[3]));
                mx = dpp_max16(mx);
                const float mnew = fmaxf(m_run[r], mx);
                alpha[r] = __builtin_amdgcn_exp2f(m_run[r] - mnew);
                float p0 = __builtin_amdgcn_exp2f(sv[0] - mnew);
                float p1 = __builtin_amdgcn_exp2f(sv[1] - mnew);
                float p2 = __builtin_amdgcn_exp2f(sv[2] - mnew);
                float p3 = __builtin_amdgcn_exp2f(sv[3] - mnew);
                float rs = dpp_sum16((p0 + p1) + (p2 + p3));
                l_run[r] = alpha[r] * l_run[r] + rs;
                m_run[r] = mnew;
                short* pr = &Ps[w][quad * 4 + r][l16];
                pr[0]  = f2bf(p0);
                pr[16] = f2bf(p1);
                pr[32] = f2bf(p2);
                pr[48] = f2bf(p3);
            }

#pragma unroll
            for (int dt = 0; dt < 8; ++dt)
#pragma unroll
                for (int r = 0; r < 4; ++r) O[dt][r] *= alpha[r];

            // PV: O[16q x 128d] += P[16q x 64k] V[64k x 128d], 2 k-steps
#pragma unroll
            for (int ks2 = 0; ks2 < 2; ++ks2) {
                bf8_t pf = *(const bf8_t*)&Ps[w][l16][ks2 * 32 + quad * 8];
#pragma unroll
                for (int dt = 0; dt < 8; ++dt) {
                    const int d = dt * 16 + l16;
                    const int slot = d * 8 + ((ks2 * 4 + quad) ^ (d & 7));
                    bf8_t vf = *(const bf8_t*)&Vs[cur][slot * 8];
                    O[dt] = __builtin_amdgcn_mfma_f32_16x16x32_bf16(pf, vf, O[dt], 0, 0, 0);
                }
            }
        }

        float inv_l[4];
#pragma unroll
        for (int r = 0; r < 4; ++r) inv_l[r] = 1.0f / l_run[r];
        short* cbase = ctx + (size_t)(b * SEQ + q0 + w * 16 + quad * 4) * HIDN
                           + h * DHD + l16;
#pragma unroll
        for (int r = 0; r < 4; ++r)
#pragma unroll
            for (int dt = 0; dt < 8; ++dt)
                cbase[(size_t)r * HIDN + dt * 16] = f2bf(O[dt][r] * inv_l[r]);
    }
}

// ---------------------------------------------------------------------------
extern "C" void kernel_launch(void* const* d_in, const int* in_sizes, int n_in,
                              void* d_out, int out_size, void* d_ws, size_t ws_size,
                              hipStream_t stream)
{
    const float* x        = (const float*)d_in[0];
    const float* Wq_down  = (const float*)d_in[1];
    const float* Wq_up    = (const float*)d_in[2];
    const float* Wq_rope  = (const float*)d_in[3];
    const float* Wkv_down = (const float*)d_in[4];
    const float* Wk_up    = (const float*)d_in[5];
    const float* Wk_rope  = (const float*)d_in[6];
    const float* Wv_up    = (const float*)d_in[7];
    const float* Wo       = (const float*)d_in[8];
    const float* bo       = (const float*)d_in[9];
    float* out = (float*)d_out;

    // workspace (bf16 shorts)
    short* ws     = (short*)d_ws;
    short* xb     = ws;                 //  8388608
    short* wdownc = ws + 8388608;       //  2162688  [Wq_down|Wkv_down|Wk_rope] 1056 rows
    short* wqur   = ws + 10551296;      //  1048576  [Wq_up | Wq_rope]
    short* wkvu   = ws + 11599872;      //  1835008  [Wk_up | Wv_up]
    short* wob    = ws + 13434880;      //  4194304
    short* qkvlat = ws + 17629184;      //  4194304  [4096][1024] = qlat|kvlat
    short* qhb    = ws + 21823488;      //  8388608  [b][h][s][128]
    short* khb    = ws + 30212096;      //  8388608  [b][h][s][128]
    short* vtw    = ws + 38600704;      //  8388608  [b][h][d][s]
    short* ctxb   = ws + 46989312;      //  8388608  [b][s][2048]
    short* qrt    = ws + 55377920;      //  2097152
    short* krt    = ws + 57475072;      //   131072

    dim3 blk(256);
    cvt_all<<<dim3(8608), blk, 0, stream>>>(
        x, Wq_down, Wq_up, Wq_rope, Wkv_down, Wk_up, Wk_rope, Wv_up, Wo,
        xb, wdownc, wqur, wqur + 786432, wdownc + 1048576,
        wkvu, wdownc + 2097152, wkvu + 786432, wob);

    gemm_t<2048, EPI_DOWN><<<dim3(32, 9), blk, 0, stream>>>(
        xb, wdownc, nullptr, qkvlat, krt, nullptr, nullptr, nullptr);
    gemm_t<512, EPI_UP><<<dim3(32, 44), blk, 0, stream>>>(
        qkvlat, wqur, wkvu, qhb, qrt, khb, vtw, nullptr);

    rope_q_kernel<<<dim3(MTOT * NH * RD / 256), blk, 0, stream>>>(qrt, qhb);
    rope_k_kernel<<<dim3(MTOT * RD / 256), blk, 0, stream>>>(krt, khb);

    attn_mfma<<<dim3(16, NH, NB), blk, 0, stream>>>(qhb, khb, vtw, ctxb);

    gemm_t<2048, EPI_WO><<<dim3(32, 16), blk, 0, stream>>>(
        ctxb, wob, nullptr, out, nullptr, nullptr, nullptr, bo);
}